// Round 6
// baseline (183.278 us; speedup 1.0000x reference)
//
#include <hip/hip_runtime.h>
#include <stdint.h>

// Problem constants (fixed by reference setup_inputs)
#define NPOS 512   // N
#define NH   64    // H
#define NM   1024  // M
#define NB   256   // B
#define NM1  511   // N-1

typedef __attribute__((ext_vector_type(8)))  short bf16x8;
typedef __attribute__((ext_vector_type(16))) float f32x16;
typedef __attribute__((ext_vector_type(4)))  float f32x4;
typedef __attribute__((ext_vector_type(4)))  int   i32x4;

#if __has_builtin(__builtin_amdgcn_exp2f)
#define EXP2F(x) __builtin_amdgcn_exp2f(x)
#else
#define EXP2F(x) __expf((x) * 0.69314718055994531f)
#endif

__device__ __forceinline__ unsigned short f2bf(float x) {
    unsigned u = __float_as_uint(x);
    u = (u + 0x7FFFu + ((u >> 16) & 1u)) >> 16;   // RNE
    return (unsigned short)u;
}
__device__ __forceinline__ int pack2(unsigned short a, unsigned short b) {
    return (int)a | ((int)b << 16);
}
// slabs before row n (n in 1..511), slab = 64 k-elems: base(n) = 32(g-1)g + (n-1-(g-1)*64)*g
__device__ __forceinline__ int slab_base(int n) {
    int g = (n + 63) >> 6;
    return 32 * (g - 1) * g + (n - 1 - (g - 1) * 64) * g;
}

// =====================================================================
// ============ PATH A (large workspace): E-precompute design ==========
// =====================================================================

// kAE: {k0 seq->bf16 + zero out, k1a BnT softmax, k1c plusT transpose,
//       kE slab-balanced masked-exp of A -> bf16 E + f32 Z partials}.
// kE: ONE block per 64-wide slab (2296 slabs, uniform work -> no stragglers).
// grid = 272 + 2296 = 2568.
__global__ __launch_bounds__(256, 4)
void kAE_prep(const float* __restrict__ seq, const float* __restrict__ Bl,
              const float* __restrict__ mem, const float* __restrict__ Al,
              unsigned short* __restrict__ seq_bf, float* __restrict__ BnT,
              float* __restrict__ plusT, unsigned short* __restrict__ Ew,
              float* __restrict__ Zpart, float* __restrict__ out) {
    const int bid = blockIdx.x, t = threadIdx.x;
    if (bid < 128) {
        // --- k0: sequences fp32 -> bf16 (exact for +/-1) ---
        if (bid == 0 && t == 0) out[0] = 0.f;
        int idx = (bid * 256 + t) * 4;
        f32x4 v = *(const f32x4*)(seq + idx);
        int2 o;
        o.x = pack2(f2bf(v.x), f2bf(v.y));
        o.y = pack2(f2bf(v.z), f2bf(v.w));
        *(int2*)(seq_bf + idx) = o;
    } else if (bid < 144) {
        // --- k1a: Bn = softmax(B_logits, axis=-1), stored transposed ---
        const int h = (bid - 128) * 4 + (t >> 6), l = t & 63;
        float v[8]; float mx = -1e30f;
#pragma unroll
        for (int j = 0; j < 8; j++) { v[j] = Bl[h * NPOS + l + 64 * j]; mx = fmaxf(mx, v[j]); }
#pragma unroll
        for (int o = 32; o; o >>= 1) mx = fmaxf(mx, __shfl_xor(mx, o));
        float s = 0.f;
#pragma unroll
        for (int j = 0; j < 8; j++) { v[j] = __expf(v[j] - mx); s += v[j]; }
#pragma unroll
        for (int o = 32; o; o >>= 1) s += __shfl_xor(s, o);
        float r = 1.0f / s;
#pragma unroll
        for (int j = 0; j < 8; j++) BnT[(l + 64 * j) * NH + h] = v[j] * r;
    } else if (bid < 272) {
        // --- k1c: plusT[n][m] via LDS 64x64 tile transpose ---
        __shared__ float sT[64][65];
        const int bb = bid - 144;
        const int mt = bb >> 3, nt = bb & 7;
        const int rr = t >> 2, cc = t & 3;
        const float* src = mem + (size_t)(mt * 64 + rr) * NPOS + nt * 64 + cc * 16;
#pragma unroll
        for (int j = 0; j < 4; j++) {
            f32x4 v = *(const f32x4*)(src + j * 4);
            sT[rr][cc * 16 + j * 4 + 0] = (v.x > 0.f) ? 1.f : 0.f;
            sT[rr][cc * 16 + j * 4 + 1] = (v.y > 0.f) ? 1.f : 0.f;
            sT[rr][cc * 16 + j * 4 + 2] = (v.z > 0.f) ? 1.f : 0.f;
            sT[rr][cc * 16 + j * 4 + 3] = (v.w > 0.f) ? 1.f : 0.f;
        }
        __syncthreads();
        float* dst = plusT + (size_t)(nt * 64 + rr) * NM + mt * 64 + cc * 16;
#pragma unroll
        for (int j = 0; j < 4; j++) {
            f32x4 o;
            o.x = sT[cc * 16 + j * 4 + 0][rr];
            o.y = sT[cc * 16 + j * 4 + 1][rr];
            o.z = sT[cc * 16 + j * 4 + 2][rr];
            o.w = sT[cc * 16 + j * 4 + 3][rr];
            *(f32x4*)(dst + j * 4) = o;
        }
    } else {
        // --- kE slab: sid -> (n, kk). Group g = ceil(n/64); n in group g
        //     contributes g slabs; cum C(g) = 32 g (g+1), C(8)=2296. ---
        const int sid = bid - 272;
        int g, Cp;
        if      (sid < 64)   { g = 1; Cp = 0;    }
        else if (sid < 192)  { g = 2; Cp = 64;   }
        else if (sid < 384)  { g = 3; Cp = 192;  }
        else if (sid < 640)  { g = 4; Cp = 384;  }
        else if (sid < 960)  { g = 5; Cp = 640;  }
        else if (sid < 1344) { g = 6; Cp = 960;  }
        else if (sid < 1792) { g = 7; Cp = 1344; }
        else                 { g = 8; Cp = 1792; }
        const int off = sid - Cp;
        const int nIdx = off / g;
        const int kk = off - nIdx * g;
        const int n = (g - 1) * 64 + 1 + nIdx;
        const int sbase = 32 * (g - 1) * g + nIdx * g;      // slab_base(n)

        const int h = t >> 2, j = t & 3;
        const int i0 = kk * 64 + j * 16;
        const float* Ar = Al + ((size_t)n * NH + h) * NPOS + i0;
        unsigned short* Er = Ew + (size_t)(sbase + kk) * 4096 + h * 64 + j * 16;

        f32x4 v0 = *(const f32x4*)(Ar + 0);
        f32x4 v1 = *(const f32x4*)(Ar + 4);
        f32x4 v2 = *(const f32x4*)(Ar + 8);
        f32x4 v3 = *(const f32x4*)(Ar + 12);
        float e[16];
        e[0]  = (i0 + 0  < n) ? __expf(v0.x) : 0.f;
        e[1]  = (i0 + 1  < n) ? __expf(v0.y) : 0.f;
        e[2]  = (i0 + 2  < n) ? __expf(v0.z) : 0.f;
        e[3]  = (i0 + 3  < n) ? __expf(v0.w) : 0.f;
        e[4]  = (i0 + 4  < n) ? __expf(v1.x) : 0.f;
        e[5]  = (i0 + 5  < n) ? __expf(v1.y) : 0.f;
        e[6]  = (i0 + 6  < n) ? __expf(v1.z) : 0.f;
        e[7]  = (i0 + 7  < n) ? __expf(v1.w) : 0.f;
        e[8]  = (i0 + 8  < n) ? __expf(v2.x) : 0.f;
        e[9]  = (i0 + 9  < n) ? __expf(v2.y) : 0.f;
        e[10] = (i0 + 10 < n) ? __expf(v2.z) : 0.f;
        e[11] = (i0 + 11 < n) ? __expf(v2.w) : 0.f;
        e[12] = (i0 + 12 < n) ? __expf(v3.x) : 0.f;
        e[13] = (i0 + 13 < n) ? __expf(v3.y) : 0.f;
        e[14] = (i0 + 14 < n) ? __expf(v3.z) : 0.f;
        e[15] = (i0 + 15 < n) ? __expf(v3.w) : 0.f;
        float zp = 0.f;
#pragma unroll
        for (int q = 0; q < 16; q++) zp += e[q];
        i32x4 w0, w1;
        w0.x = pack2(f2bf(e[0]),  f2bf(e[1]));  w0.y = pack2(f2bf(e[2]),  f2bf(e[3]));
        w0.z = pack2(f2bf(e[4]),  f2bf(e[5]));  w0.w = pack2(f2bf(e[6]),  f2bf(e[7]));
        w1.x = pack2(f2bf(e[8]),  f2bf(e[9]));  w1.y = pack2(f2bf(e[10]), f2bf(e[11]));
        w1.z = pack2(f2bf(e[12]), f2bf(e[13])); w1.w = pack2(f2bf(e[14]), f2bf(e[15]));
        *(i32x4*)(Er)     = w0;
        *(i32x4*)(Er + 8) = w1;
        zp += __shfl_xor(zp, 1);
        zp += __shfl_xor(zp, 2);
        if (j == 0) Zpart[((size_t)(n - 1) * 8 + kk) * 64 + h] = zp;
    }
}

// ---------------- k1b: phi_mu[m,h] = sum_n Bn[h,n]*memory[m,n] -> bf16 -------
// (shared by both paths) PRE-SCALED by log2(e).
__global__ __launch_bounds__(256, 4)
void k1b_phimu(const float* __restrict__ BnT, const float* __restrict__ mem,
               unsigned short* __restrict__ phimu) {
    const int m0 = blockIdx.x * 2, t = threadIdx.x;
    __shared__ float mrow[2][NPOS];
    __shared__ float part[2][256];
    {
        int row = t >> 7, c = (t & 127) * 4;
        *(f32x4*)(&mrow[row][c]) = *(const f32x4*)(mem + (size_t)(m0 + row) * NPOS + c);
    }
    __syncthreads();
    const int h = t & 63, seg = t >> 6;
    float a[2] = {0.f, 0.f};
    float b2[2] = {0.f, 0.f};
    const float* bp = BnT + seg * 128 * NH + h;
#pragma unroll 8
    for (int nn = 0; nn < 128; nn += 2) {
        float x0 = bp[nn * NH], x1 = bp[(nn + 1) * NH];
#pragma unroll
        for (int row = 0; row < 2; row++) {
            a[row]  = fmaf(x0, mrow[row][seg * 128 + nn], a[row]);
            b2[row] = fmaf(x1, mrow[row][seg * 128 + nn + 1], b2[row]);
        }
    }
#pragma unroll
    for (int row = 0; row < 2; row++) part[row][t] = a[row] + b2[row];
    __syncthreads();
    if (t < 64) {
#pragma unroll
        for (int row = 0; row < 2; row++) {
            float s = (part[row][t] + part[row][t + 64]) + (part[row][t + 128] + part[row][t + 192]);
            phimu[(m0 + row) * NH + t] = f2bf(s * 1.4426950408889634f);  // * log2(e)
        }
    }
}

// ------------- phase-2 helper (static indexing only; rule #20) ---------------
__device__ __forceinline__ void p2_load(bf16x8 (&p)[4], const unsigned short* __restrict__ phimu,
                                        int tile, int r, int half) {
#pragma unroll
    for (int kq = 0; kq < 4; kq++)
        p[kq] = *(const bf16x8*)(phimu + (size_t)(tile * 32 + r) * NH + kq * 16 + half * 8);
}

// ---------------- k23E: b-split (128 b/block), grid 1022 ---------------------
// 4 waves x 32 b each. LDS ~23.6 KB (q tile UNIONs the dead E double-buffer)
// -> 4 blocks/CU resident = 16 waves/CU = 4 waves/SIMD (~3x round-5 waves),
// with ZERO duplicated FLOPs (E + Z precomputed; pair blocks re-read L3-hot E).
__global__ __launch_bounds__(256, 4)
void k23_fusedE(const unsigned short* __restrict__ Ew, const float* __restrict__ Zpart,
                const unsigned short* __restrict__ seq_bf,
                const unsigned short* __restrict__ phimu, const float* __restrict__ plusT,
                const float* __restrict__ seq, float* __restrict__ out) {
    __shared__ __align__(16) unsigned short u_lds[9216];  // union: E dbuf (2x64x72) / q (128x72)
    __shared__ float s_plus[NM];
    __shared__ float dn_lds[256];                         // 128 den + 128 num
    __shared__ float w_lds[4];

    const int t = threadIdx.x;
    const int u = blockIdx.x >> 1, bh = blockIdx.x & 1;
    const int n = (u & 1) ? (1 + (u >> 1)) : (NM1 - (u >> 1));   // big/small pairing
    const int boff = bh << 7;
    const int ksteps = (n + 63) >> 6;
    const int wv = t >> 6, lane = t & 63, half = lane >> 5, r = lane & 31;

    // stage plus row + Z (sum of per-slab partials; ready since launch 1)
    *(f32x4*)(s_plus + t * 4) = *(const f32x4*)(plusT + (size_t)n * NM + t * 4);
    float Zr0 = 0.f, Zr1 = 0.f;
    for (int kk = 0; kk < ksteps; kk++) {
        const float* zp = Zpart + ((size_t)(n - 1) * 8 + kk) * 64;
        Zr0 += zp[r];
        Zr1 += zp[32 + r];
    }

    // ================= phase 1: hat_phi tile (128 b x 64 h) =================
    const unsigned short* Eb = Ew + (size_t)slab_base(n) * 4096;
    const int eh = t >> 2, ec = (t & 3) * 16;                    // E staging map
    const unsigned short* s0 = seq_bf + (size_t)(boff + wv * 32 + r) * NPOS;

    f32x16 acc0, acc1;
#pragma unroll
    for (int i = 0; i < 16; i++) { acc0[i] = 0.f; acc1[i] = 0.f; }

    bf16x8 er0, er1, sc0[4], sn0[4];
    er0 = *(const bf16x8*)(Eb + eh * 64 + ec);
    er1 = *(const bf16x8*)(Eb + eh * 64 + ec + 8);
#pragma unroll
    for (int kq = 0; kq < 4; kq++)
        sc0[kq] = *(const bf16x8*)(s0 + kq * 16 + half * 8);

    for (int kk = 0; kk < ksteps; kk++) {
        unsigned short* ebuf = u_lds + (kk & 1) * 4608;          // 64*72 shorts
        // 1. stage E tile from regs
        {
            unsigned short* ep = ebuf + eh * 72 + ec;
            *(bf16x8*)(ep)     = er0;
            *(bf16x8*)(ep + 8) = er1;
        }
        // 2. prefetch k+1 (stays in flight across the raw barrier)
        if (kk + 1 < ksteps) {
            const unsigned short* nb = Eb + (kk + 1) * 4096 + eh * 64 + ec;
            er0 = *(const bf16x8*)(nb);
            er1 = *(const bf16x8*)(nb + 8);
            const int k0 = (kk + 1) * 64;
#pragma unroll
            for (int kq = 0; kq < 4; kq++)
                sn0[kq] = *(const bf16x8*)(s0 + k0 + kq * 16 + half * 8);
        }
        // 3. LDS-only fence + raw barrier (global prefetches NOT drained)
        asm volatile("s_waitcnt lgkmcnt(0)" ::: "memory");
        __builtin_amdgcn_s_barrier();
        asm volatile("" ::: "memory");
        // 4. MFMA: D[b][h] += S[b,i] * E[h,i]  (8 MFMA, 2 independent chains)
        {
            const unsigned short* sB0 = ebuf + r * 72;
            const unsigned short* sB1 = sB0 + 32 * 72;
#pragma unroll
            for (int kq = 0; kq < 4; kq++) {
                const int ko = kq * 16 + half * 8;
                bf16x8 B0 = *(const bf16x8*)(sB0 + ko);
                bf16x8 B1 = *(const bf16x8*)(sB1 + ko);
                acc0 = __builtin_amdgcn_mfma_f32_32x32x16_bf16(sc0[kq], B0, acc0, 0, 0, 0);
                acc1 = __builtin_amdgcn_mfma_f32_32x32x16_bf16(sc0[kq], B1, acc1, 0, 0, 0);
            }
        }
        // 5. rotate S fragments
        if (kk + 1 < ksteps) {
#pragma unroll
            for (int kq = 0; kq < 4; kq++) sc0[kq] = sn0[kq];
        }
    }
    // union hazard: all waves must finish reading E before q overwrites u_lds
    __syncthreads();
    // epilogue: scale by 1/Z[h], write q tile (wave-own 32 rows, stride 72)
    {
        float rz0 = 1.0f / Zr0;
        float rz1 = 1.0f / Zr1;
#pragma unroll
        for (int reg = 0; reg < 16; reg++) {
            int row = (reg & 3) + 8 * (reg >> 2) + 4 * half;
            u_lds[(wv * 32 + row) * 72 + r]      = f2bf(acc0[reg] * rz0);
            u_lds[(wv * 32 + row) * 72 + 32 + r] = f2bf(acc1[reg] * rz1);
        }
    }

    // ================= phase 2: retrieval softmax (wave owns 32 b) ==========
    bf16x8 p[4], pn[4];
    p2_load(p, phimu, 0, r, half);             // global loads issue first
    bf16x8 q0[4];
#pragma unroll
    for (int kq = 0; kq < 4; kq++)
        q0[kq] = *(const bf16x8*)(u_lds + (wv * 32 + r) * 72 + kq * 16 + half * 8);
    f32x16 zacc;
#pragma unroll
    for (int i = 0; i < 16; i++) zacc[i] = 0.f;

    f32x4 den = {0.f,0.f,0.f,0.f}, num = {0.f,0.f,0.f,0.f};
    f32x16 a0;

    for (int it = 0; it < 32; ++it) {
        if (it < 31) p2_load(pn, phimu, it + 1, r, half);   // prefetch, no barrier
        a0 = __builtin_amdgcn_mfma_f32_32x32x16_bf16(p[0], q0[0], zacc, 0, 0, 0);
#pragma unroll
        for (int kq = 1; kq < 4; kq++)
            a0 = __builtin_amdgcn_mfma_f32_32x32x16_bf16(p[kq], q0[kq], a0, 0, 0, 0);
        const int mb = it * 32;
#pragma unroll
        for (int g2 = 0; g2 < 4; g2++) {
            f32x4 pv = *(const f32x4*)(s_plus + mb + 4 * half + 8 * g2);
            f32x4 e;
#pragma unroll
            for (int j = 0; j < 4; j++) e[j] = EXP2F(a0[4 * g2 + j]);  // m = mb + j + 8*g2 + 4*half
            den += e; num += e * pv;
        }
        if (it < 31) {
#pragma unroll
            for (int kq = 0; kq < 4; kq++) p[kq] = pn[kq];
        }
    }

    float d  = (den[0] + den[1]) + (den[2] + den[3]);
    float nu = (num[0] + num[1]) + (num[2] + num[3]);
    // combine the two m-halves (same b, complementary m rows)
    d += __shfl_xor(d, 32); nu += __shfl_xor(nu, 32);

    if (half == 0) { dn_lds[wv * 32 + r] = d; dn_lds[128 + wv * 32 + r] = nu; }
    __syncthreads();
    // BCE for b_local = t (t < 128)
    float bce = 0.f;
    if (t < 128) {
        float dd = dn_lds[t], nn2 = dn_lds[128 + t];
        float p2 = nn2 / dd;
        p2 = fminf(fmaxf(p2, 1e-6f), 1.0f - 1e-6f);
        float tg = seq[(size_t)(boff + t) * NPOS + n];
        bce = (tg > 0.f) ? -logf(p2) : -logf(1.0f - p2);
    }
#pragma unroll
    for (int o = 32; o; o >>= 1) bce += __shfl_xor(bce, o);
    if (lane == 0) w_lds[wv] = bce;
    __syncthreads();
    if (t == 0)
        atomicAdd(out, (w_lds[0] + w_lds[1] + w_lds[2] + w_lds[3]) * (1.0f / 130816.0f));
}

// =====================================================================
// ====== PATH B (small workspace): round-0 kernels, verbatim ==========
// =====================================================================

__global__ __launch_bounds__(256, 4)
void kA_prep(const float* __restrict__ seq, const float* __restrict__ Bl,
             const float* __restrict__ mem,
             unsigned short* __restrict__ seq_bf, float* __restrict__ BnT,
             float* __restrict__ plusT, float* __restrict__ out) {
    const int bid = blockIdx.x, t = threadIdx.x;
    if (bid < 128) {
        if (bid == 0 && t == 0) out[0] = 0.f;
        int idx = (bid * 256 + t) * 4;
        f32x4 v = *(const f32x4*)(seq + idx);
        int2 o;
        o.x = pack2(f2bf(v.x), f2bf(v.y));
        o.y = pack2(f2bf(v.z), f2bf(v.w));
        *(int2*)(seq_bf + idx) = o;
    } else if (bid < 144) {
        const int h = (bid - 128) * 4 + (t >> 6), l = t & 63;
        float v[8]; float mx = -1e30f;
#pragma unroll
        for (int j = 0; j < 8; j++) { v[j] = Bl[h * NPOS + l + 64 * j]; mx = fmaxf(mx, v[j]); }
#pragma unroll
        for (int o = 32; o; o >>= 1) mx = fmaxf(mx, __shfl_xor(mx, o));
        float s = 0.f;
#pragma unroll
        for (int j = 0; j < 8; j++) { v[j] = __expf(v[j] - mx); s += v[j]; }
#pragma unroll
        for (int o = 32; o; o >>= 1) s += __shfl_xor(s, o);
        float r = 1.0f / s;
#pragma unroll
        for (int j = 0; j < 8; j++) BnT[(l + 64 * j) * NH + h] = v[j] * r;
    } else {
        __shared__ float sT[64][65];
        const int bb = bid - 144;
        const int mt = bb >> 3, nt = bb & 7;
        const int rr = t >> 2, cc = t & 3;
        const float* src = mem + (size_t)(mt * 64 + rr) * NPOS + nt * 64 + cc * 16;
#pragma unroll
        for (int j = 0; j < 4; j++) {
            f32x4 v = *(const f32x4*)(src + j * 4);
            sT[rr][cc * 16 + j * 4 + 0] = (v.x > 0.f) ? 1.f : 0.f;
            sT[rr][cc * 16 + j * 4 + 1] = (v.y > 0.f) ? 1.f : 0.f;
            sT[rr][cc * 16 + j * 4 + 2] = (v.z > 0.f) ? 1.f : 0.f;
            sT[rr][cc * 16 + j * 4 + 3] = (v.w > 0.f) ? 1.f : 0.f;
        }
        __syncthreads();
        float* dst = plusT + (size_t)(nt * 64 + rr) * NM + mt * 64 + cc * 16;
#pragma unroll
        for (int j = 0; j < 4; j++) {
            f32x4 o;
            o.x = sT[cc * 16 + j * 4 + 0][rr];
            o.y = sT[cc * 16 + j * 4 + 1][rr];
            o.z = sT[cc * 16 + j * 4 + 2][rr];
            o.w = sT[cc * 16 + j * 4 + 3][rr];
            *(f32x4*)(dst + j * 4) = o;
        }
    }
}

__global__ __launch_bounds__(256, 2)
void k23_fused0(const float* __restrict__ Al, const unsigned short* __restrict__ seq_bf,
                const unsigned short* __restrict__ phimu, const float* __restrict__ plusT,
                const float* __restrict__ seq, float* __restrict__ out) {
    __shared__ __align__(16) unsigned short s_lds[256 * 72];
    __shared__ __align__(16) unsigned short e_lds[64 * 72];
    __shared__ float z_lds[64];
    __shared__ float s_plus[NM];

    const int t = threadIdx.x;
    const int n = NM1 - (int)blockIdx.x;
    const int ksteps = (n + 63) >> 6;
    const int wv = t >> 6, lane = t & 63, half = lane >> 5, r = lane & 31;

    if (t < 64) z_lds[t] = 0.f;
    *(f32x4*)(s_plus + t * 4) = *(const f32x4*)(plusT + n * NM + t * 4);

    const int eh = t >> 2, ei = (t & 3) * 16;
    const float* arow = Al + ((size_t)n * NH + eh) * NPOS + ei;
    const unsigned short* srcS = seq_bf + (size_t)t * NPOS;

    f32x16 acc00, acc01, acc10, acc11;
#pragma unroll
    for (int i = 0; i < 16; i++) { acc00[i] = 0.f; acc01[i] = 0.f; acc10[i] = 0.f; acc11[i] = 0.f; }

    f32x4 ea[4]; i32x4 sa[8];
#pragma unroll
    for (int g = 0; g < 4; g++) ea[g] = *(const f32x4*)(arow + g * 4);
#pragma unroll
    for (int c = 0; c < 8; c++) sa[c] = *(const i32x4*)(srcS + c * 8);
    __syncthreads();

    for (int kk = 0; kk < ksteps; kk++) {
        const int k0 = kk * 64;
        {
            float zp = 0.f;
            unsigned short* ep = e_lds + eh * 72 + ei;
#pragma unroll
            for (int g = 0; g < 4; g++) {
                int i0 = k0 + ei + g * 4;
                float e0 = (i0 + 0 < n) ? __expf(ea[g].x) : 0.f;
                float e1 = (i0 + 1 < n) ? __expf(ea[g].y) : 0.f;
                float e2 = (i0 + 2 < n) ? __expf(ea[g].z) : 0.f;
                float e3 = (i0 + 3 < n) ? __expf(ea[g].w) : 0.f;
                zp += (e0 + e1) + (e2 + e3);
                int2 o; o.x = pack2(f2bf(e0), f2bf(e1)); o.y = pack2(f2bf(e2), f2bf(e3));
                *(int2*)(ep + g * 4) = o;
            }
            zp += __shfl_xor(zp, 1);
            zp += __shfl_xor(zp, 2);
            if ((t & 3) == 0) z_lds[eh] += zp;
        }
        {
            unsigned short* dp = s_lds + t * 72;
#pragma unroll
            for (int c = 0; c < 8; c++) *(i32x4*)(dp + c * 8) = sa[c];
        }
        __syncthreads();
        if (kk + 1 < ksteps) {
#pragma unroll
            for (int g = 0; g < 4; g++) ea[g] = *(const f32x4*)(arow + k0 + 64 + g * 4);
#pragma unroll
            for (int c = 0; c < 8; c++) sa[c] = *(const i32x4*)(srcS + k0 + 64 + c * 8);
        }
        {
            const unsigned short* sA0 = s_lds + (wv * 64 + r) * 72;
            const unsigned short* sA1 = sA0 + 32 * 72;
            const unsigned short* sB0 = e_lds + r * 72;
            const unsigned short* sB1 = sB0 + 32 * 72;
#pragma unroll
            for (int kq = 0; kq < 4; kq++) {
                const int ko = kq * 16 + half * 8;
                bf16x8 A0 = *(const bf16x8*)(sA0 + ko);
                bf16x8 A1 = *(const bf16x8*)(sA1 + ko);
                bf16x8 B0 = *(const bf16x8*)(sB0 + ko);
                bf16x8 B1 = *(const bf16x8*)(sB1 + ko);
                acc00 = __builtin_amdgcn_mfma_f32_32x32x16_bf16(A0, B0, acc00, 0, 0, 0);
                acc01 = __builtin_amdgcn_mfma_f32_32x32x16_bf16(A0, B1, acc01, 0, 0, 0);
                acc10 = __builtin_amdgcn_mfma_f32_32x32x16_bf16(A1, B0, acc10, 0, 0, 0);
                acc11 = __builtin_amdgcn_mfma_f32_32x32x16_bf16(A1, B1, acc11, 0, 0, 0);
            }
        }
        __syncthreads();
    }
    {
        float rz0 = 1.0f / z_lds[r];
        float rz1 = 1.0f / z_lds[32 + r];
#pragma unroll
        for (int reg = 0; reg < 16; reg++) {
            int row = (reg & 3) + 8 * (reg >> 2) + 4 * half;
            s_lds[(wv * 64 + row) * 72 + r]            = f2bf(acc00[reg] * rz0);
            s_lds[(wv * 64 + row) * 72 + 32 + r]       = f2bf(acc01[reg] * rz1);
            s_lds[(wv * 64 + 32 + row) * 72 + r]       = f2bf(acc10[reg] * rz0);
            s_lds[(wv * 64 + 32 + row) * 72 + 32 + r]  = f2bf(acc11[reg] * rz1);
        }
    }
    __syncthreads();

    bf16x8 p[4];
#pragma unroll
    for (int kq = 0; kq < 4; kq++)
        p[kq] = *(const bf16x8*)(phimu + (r) * NH + kq * 16 + half * 8);
    bf16x8 q[2][4];
#pragma unroll
    for (int bs = 0; bs < 2; bs++)
#pragma unroll
        for (int kq = 0; kq < 4; kq++)
            q[bs][kq] = *(const bf16x8*)(s_lds + (wv * 64 + bs * 32 + r) * 72 + kq * 16 + half * 8);

    f32x4 den0 = {0.f,0.f,0.f,0.f}, num0 = {0.f,0.f,0.f,0.f};
    f32x4 den1 = {0.f,0.f,0.f,0.f}, num1 = {0.f,0.f,0.f,0.f};

    for (int it = 0; it < 32; ++it) {
        bf16x8 pn[4];
        if (it < 31) {
#pragma unroll
            for (int kq = 0; kq < 4; kq++)
                pn[kq] = *(const bf16x8*)(phimu + ((it + 1) * 32 + r) * NH + kq * 16 + half * 8);
        }
        f32x16 a0, a1;
#pragma unroll
        for (int i = 0; i < 16; i++) { a0[i] = 0.f; a1[i] = 0.f; }
#pragma unroll
        for (int kq = 0; kq < 4; kq++) {
            a0 = __builtin_amdgcn_mfma_f32_32x32x16_bf16(p[kq], q[0][kq], a0, 0, 0, 0);
            a1 = __builtin_amdgcn_mfma_f32_32x32x16_bf16(p[kq], q[1][kq], a1, 0, 0, 0);
        }
        const int mb = it * 32;
        f32x4 pv[4];
#pragma unroll
        for (int g = 0; g < 4; g++) pv[g] = *(const f32x4*)(s_plus + mb + 4 * half + 8 * g);
#pragma unroll
        for (int g = 0; g < 4; g++) {
            f32x4 e0, e1;
#pragma unroll
            for (int j = 0; j < 4; j++) {
                e0[j] = EXP2F(a0[4 * g + j]);
                e1[j] = EXP2F(a1[4 * g + j]);
            }
            den0 += e0; num0 += e0 * pv[g];
            den1 += e1; num1 += e1 * pv[g];
        }
        if (it < 31) {
#pragma unroll
            for (int kq = 0; kq < 4; kq++) p[kq] = pn[kq];
        }
    }
    float d0 = (den0[0] + den0[1]) + (den0[2] + den0[3]);
    float nu0 = (num0[0] + num0[1]) + (num0[2] + num0[3]);
    float d1 = (den1[0] + den1[1]) + (den1[2] + den1[3]);
    float nu1 = (num1[0] + num1[1]) + (num1[2] + num1[3]);
    d0 += __shfl_xor(d0, 32); nu0 += __shfl_xor(nu0, 32);
    d1 += __shfl_xor(d1, 32); nu1 += __shfl_xor(nu1, 32);

    float* dsum = (float*)e_lds;
    float* nsum = dsum + 256;
    if (half == 0) {
        dsum[wv * 64 + r]      = d0; nsum[wv * 64 + r]      = nu0;
        dsum[wv * 64 + 32 + r] = d1; nsum[wv * 64 + 32 + r] = nu1;
    }
    __syncthreads();
    {
        float dd = dsum[t], nn = nsum[t];
        float p2 = nn / dd;
        p2 = fminf(fmaxf(p2, 1e-6f), 1.0f - 1e-6f);
        float tg = seq[(size_t)t * NPOS + n];
        float bce = (tg > 0.f) ? -logf(p2) : -logf(1.0f - p2);
#pragma unroll
        for (int o = 32; o; o >>= 1) bce += __shfl_xor(bce, o);
        if (lane == 0) z_lds[wv] = bce;
    }
    __syncthreads();
    if (t == 0)
        atomicAdd(out, (z_lds[0] + z_lds[1] + z_lds[2] + z_lds[3]) * (1.0f / 130816.0f));
}

extern "C" void kernel_launch(void* const* d_in, const int* in_sizes, int n_in,
                              void* d_out, int out_size, void* d_ws, size_t ws_size,
                              hipStream_t stream) {
    const float* seq = (const float*)d_in[0];  // (B,N)
    const float* mem = (const float*)d_in[1];  // (M,N)
    const float* Al  = (const float*)d_in[2];  // (N,H,N)
    const float* Bl  = (const float*)d_in[3];  // (H,N)

    char* ws = (char*)d_ws;
    unsigned short* seq_bf = (unsigned short*)(ws + 0);          // 256 KB
    float*          BnT    = (float*)(ws + 262144);              // 128 KB (N,H)
    unsigned short* phimu  = (unsigned short*)(ws + 393216);     // 128 KB (M,H) *log2e
    float*          plusT  = (float*)(ws + 524288);              // 2 MB (N,M)
    float*          Zpart  = (float*)(ws + 2621440);             // 1 MB (N-1,8,64) Z partials
    unsigned short* Ew     = (unsigned short*)(ws + 3670016);    // 18.8 MB exact-slab bf16 E
    float*          outp   = (float*)d_out;

    // Ew end = 3,670,016 + 2296 slabs * 8192 B = 22,478,848 (R5 proved >=36.2 MB available)
    const size_t WS_NEEDED_E = 3670016 + (size_t)2296 * 8192;

    if (ws_size >= WS_NEEDED_E) {
        // PATH A: E-precompute (slab-balanced) + b-split fused kernel
        kAE_prep<<<2568, 256, 0, stream>>>(seq, Bl, mem, Al, seq_bf, BnT, plusT, Ew, Zpart, outp);
        k1b_phimu<<<512, 256, 0, stream>>>(BnT, mem, phimu);
        k23_fusedE<<<1022, 256, 0, stream>>>(Ew, Zpart, seq_bf, phimu, plusT, seq, outp);
    } else {
        // PATH B: round-0 proven kernels (145.6 us, absmax 0.0)
        kA_prep<<<272, 256, 0, stream>>>(seq, Bl, mem, seq_bf, BnT, plusT, outp);
        k1b_phimu<<<512, 256, 0, stream>>>(BnT, mem, phimu);
        k23_fused0<<<511, 256, 0, stream>>>(Al, seq_bf, phimu, plusT, seq, outp);
    }
}

// Round 7
// 153.954 us; speedup vs baseline: 1.1905x; 1.1905x over previous
//
#include <hip/hip_runtime.h>
#include <stdint.h>

// Problem constants (fixed by reference setup_inputs)
#define NPOS 512   // N
#define NH   64    // H
#define NM   1024  // M
#define NB   256   // B
#define NM1  511   // N-1

typedef __attribute__((ext_vector_type(8)))  short bf16x8;
typedef __attribute__((ext_vector_type(16))) float f32x16;
typedef __attribute__((ext_vector_type(4)))  float f32x4;
typedef __attribute__((ext_vector_type(4)))  int   i32x4;

#if __has_builtin(__builtin_amdgcn_exp2f)
#define EXP2F(x) __builtin_amdgcn_exp2f(x)
#else
#define EXP2F(x) __expf((x) * 0.69314718055994531f)
#endif

__device__ __forceinline__ unsigned short f2bf(float x) {
    unsigned u = __float_as_uint(x);
    u = (u + 0x7FFFu + ((u >> 16) & 1u)) >> 16;   // RNE
    return (unsigned short)u;
}
__device__ __forceinline__ int pack2(unsigned short a, unsigned short b) {
    return (int)a | ((int)b << 16);
}
// slabs before row n (n in 1..511), slab = 64 k-elems
__device__ __forceinline__ int slab_base(int n) {
    int g = (n + 63) >> 6;
    return 32 * (g - 1) * g + (n - 1 - (g - 1) * 64) * g;
}

// =====================================================================
// ============ PATH A (large workspace): E-precompute design ==========
// =====================================================================

// kAE: {k0 seq->bf16 + zero out, k1a BnT softmax, k1c plusT transpose,
//       kE slab-balanced masked-exp of A -> bf16 E + f32 Z partials}.
// grid = 272 + 2296 = 2568.  (unchanged from R5 — measured good)
__global__ __launch_bounds__(256, 4)
void kAE_prep(const float* __restrict__ seq, const float* __restrict__ Bl,
              const float* __restrict__ mem, const float* __restrict__ Al,
              unsigned short* __restrict__ seq_bf, float* __restrict__ BnT,
              float* __restrict__ plusT, unsigned short* __restrict__ Ew,
              float* __restrict__ Zpart, float* __restrict__ out) {
    const int bid = blockIdx.x, t = threadIdx.x;
    if (bid < 128) {
        // --- k0: sequences fp32 -> bf16 (exact for +/-1) ---
        if (bid == 0 && t == 0) out[0] = 0.f;
        int idx = (bid * 256 + t) * 4;
        f32x4 v = *(const f32x4*)(seq + idx);
        int2 o;
        o.x = pack2(f2bf(v.x), f2bf(v.y));
        o.y = pack2(f2bf(v.z), f2bf(v.w));
        *(int2*)(seq_bf + idx) = o;
    } else if (bid < 144) {
        // --- k1a: Bn = softmax(B_logits, axis=-1), stored transposed ---
        const int h = (bid - 128) * 4 + (t >> 6), l = t & 63;
        float v[8]; float mx = -1e30f;
#pragma unroll
        for (int j = 0; j < 8; j++) { v[j] = Bl[h * NPOS + l + 64 * j]; mx = fmaxf(mx, v[j]); }
#pragma unroll
        for (int o = 32; o; o >>= 1) mx = fmaxf(mx, __shfl_xor(mx, o));
        float s = 0.f;
#pragma unroll
        for (int j = 0; j < 8; j++) { v[j] = __expf(v[j] - mx); s += v[j]; }
#pragma unroll
        for (int o = 32; o; o >>= 1) s += __shfl_xor(s, o);
        float r = 1.0f / s;
#pragma unroll
        for (int j = 0; j < 8; j++) BnT[(l + 64 * j) * NH + h] = v[j] * r;
    } else if (bid < 272) {
        // --- k1c: plusT[n][m] via LDS 64x64 tile transpose ---
        __shared__ float sT[64][65];
        const int bb = bid - 144;
        const int mt = bb >> 3, nt = bb & 7;
        const int rr = t >> 2, cc = t & 3;
        const float* src = mem + (size_t)(mt * 64 + rr) * NPOS + nt * 64 + cc * 16;
#pragma unroll
        for (int j = 0; j < 4; j++) {
            f32x4 v = *(const f32x4*)(src + j * 4);
            sT[rr][cc * 16 + j * 4 + 0] = (v.x > 0.f) ? 1.f : 0.f;
            sT[rr][cc * 16 + j * 4 + 1] = (v.y > 0.f) ? 1.f : 0.f;
            sT[rr][cc * 16 + j * 4 + 2] = (v.z > 0.f) ? 1.f : 0.f;
            sT[rr][cc * 16 + j * 4 + 3] = (v.w > 0.f) ? 1.f : 0.f;
        }
        __syncthreads();
        float* dst = plusT + (size_t)(nt * 64 + rr) * NM + mt * 64 + cc * 16;
#pragma unroll
        for (int j = 0; j < 4; j++) {
            f32x4 o;
            o.x = sT[cc * 16 + j * 4 + 0][rr];
            o.y = sT[cc * 16 + j * 4 + 1][rr];
            o.z = sT[cc * 16 + j * 4 + 2][rr];
            o.w = sT[cc * 16 + j * 4 + 3][rr];
            *(f32x4*)(dst + j * 4) = o;
        }
    } else {
        // --- kE slab: sid -> (n, kk). Group g = ceil(n/64). ---
        const int sid = bid - 272;
        int g, Cp;
        if      (sid < 64)   { g = 1; Cp = 0;    }
        else if (sid < 192)  { g = 2; Cp = 64;   }
        else if (sid < 384)  { g = 3; Cp = 192;  }
        else if (sid < 640)  { g = 4; Cp = 384;  }
        else if (sid < 960)  { g = 5; Cp = 640;  }
        else if (sid < 1344) { g = 6; Cp = 960;  }
        else if (sid < 1792) { g = 7; Cp = 1344; }
        else                 { g = 8; Cp = 1792; }
        const int off = sid - Cp;
        const int nIdx = off / g;
        const int kk = off - nIdx * g;
        const int n = (g - 1) * 64 + 1 + nIdx;
        const int sbase = 32 * (g - 1) * g + nIdx * g;      // slab_base(n)

        const int h = t >> 2, j = t & 3;
        const int i0 = kk * 64 + j * 16;
        const float* Ar = Al + ((size_t)n * NH + h) * NPOS + i0;
        unsigned short* Er = Ew + (size_t)(sbase + kk) * 4096 + h * 64 + j * 16;

        f32x4 v0 = *(const f32x4*)(Ar + 0);
        f32x4 v1 = *(const f32x4*)(Ar + 4);
        f32x4 v2 = *(const f32x4*)(Ar + 8);
        f32x4 v3 = *(const f32x4*)(Ar + 12);
        float e[16];
        e[0]  = (i0 + 0  < n) ? __expf(v0.x) : 0.f;
        e[1]  = (i0 + 1  < n) ? __expf(v0.y) : 0.f;
        e[2]  = (i0 + 2  < n) ? __expf(v0.z) : 0.f;
        e[3]  = (i0 + 3  < n) ? __expf(v0.w) : 0.f;
        e[4]  = (i0 + 4  < n) ? __expf(v1.x) : 0.f;
        e[5]  = (i0 + 5  < n) ? __expf(v1.y) : 0.f;
        e[6]  = (i0 + 6  < n) ? __expf(v1.z) : 0.f;
        e[7]  = (i0 + 7  < n) ? __expf(v1.w) : 0.f;
        e[8]  = (i0 + 8  < n) ? __expf(v2.x) : 0.f;
        e[9]  = (i0 + 9  < n) ? __expf(v2.y) : 0.f;
        e[10] = (i0 + 10 < n) ? __expf(v2.z) : 0.f;
        e[11] = (i0 + 11 < n) ? __expf(v2.w) : 0.f;
        e[12] = (i0 + 12 < n) ? __expf(v3.x) : 0.f;
        e[13] = (i0 + 13 < n) ? __expf(v3.y) : 0.f;
        e[14] = (i0 + 14 < n) ? __expf(v3.z) : 0.f;
        e[15] = (i0 + 15 < n) ? __expf(v3.w) : 0.f;
        float zp = 0.f;
#pragma unroll
        for (int q = 0; q < 16; q++) zp += e[q];
        i32x4 w0, w1;
        w0.x = pack2(f2bf(e[0]),  f2bf(e[1]));  w0.y = pack2(f2bf(e[2]),  f2bf(e[3]));
        w0.z = pack2(f2bf(e[4]),  f2bf(e[5]));  w0.w = pack2(f2bf(e[6]),  f2bf(e[7]));
        w1.x = pack2(f2bf(e[8]),  f2bf(e[9]));  w1.y = pack2(f2bf(e[10]), f2bf(e[11]));
        w1.z = pack2(f2bf(e[12]), f2bf(e[13])); w1.w = pack2(f2bf(e[14]), f2bf(e[15]));
        *(i32x4*)(Er)     = w0;
        *(i32x4*)(Er + 8) = w1;
        zp += __shfl_xor(zp, 1);
        zp += __shfl_xor(zp, 2);
        if (j == 0) Zpart[((size_t)(n - 1) * 8 + kk) * 64 + h] = zp;
    }
}

// ---------------- k1b: phi_mu[m,h] (unchanged, PRE-SCALED by log2(e)) --------
__global__ __launch_bounds__(256, 4)
void k1b_phimu(const float* __restrict__ BnT, const float* __restrict__ mem,
               unsigned short* __restrict__ phimu) {
    const int m0 = blockIdx.x * 2, t = threadIdx.x;
    __shared__ float mrow[2][NPOS];
    __shared__ float part[2][256];
    {
        int row = t >> 7, c = (t & 127) * 4;
        *(f32x4*)(&mrow[row][c]) = *(const f32x4*)(mem + (size_t)(m0 + row) * NPOS + c);
    }
    __syncthreads();
    const int h = t & 63, seg = t >> 6;
    float a[2] = {0.f, 0.f};
    float b2[2] = {0.f, 0.f};
    const float* bp = BnT + seg * 128 * NH + h;
#pragma unroll 8
    for (int nn = 0; nn < 128; nn += 2) {
        float x0 = bp[nn * NH], x1 = bp[(nn + 1) * NH];
#pragma unroll
        for (int row = 0; row < 2; row++) {
            a[row]  = fmaf(x0, mrow[row][seg * 128 + nn], a[row]);
            b2[row] = fmaf(x1, mrow[row][seg * 128 + nn + 1], b2[row]);
        }
    }
#pragma unroll
    for (int row = 0; row < 2; row++) part[row][t] = a[row] + b2[row];
    __syncthreads();
    if (t < 64) {
#pragma unroll
        for (int row = 0; row < 2; row++) {
            float s = (part[row][t] + part[row][t + 64]) + (part[row][t + 128] + part[row][t + 192]);
            phimu[(m0 + row) * NH + t] = f2bf(s * 1.4426950408889634f);  // * log2(e)
        }
    }
}

// ------------- phase-2 helper (static indexing only; rule #20) ---------------
__device__ __forceinline__ void p2_load(bf16x8 (&p)[4], const unsigned short* __restrict__ phimu,
                                        int tile, int r, int half) {
#pragma unroll
    for (int kq = 0; kq < 4; kq++)
        p[kq] = *(const bf16x8*)(phimu + (size_t)(tile * 32 + r) * NH + kq * 16 + half * 8);
}

// ---------------- k23E v2: grid 511, 512 thr = 8 waves -----------------------
// Same per-n loop count and memory traffic as R5 (52.7 us); 2x waves/SIMD.
// Phase 1: 8 waves x 32 b x 64 h (2 chains each; chains/SIMD same as R5).
// Phase 2: wave = (m-half mh, b-group wg): 64 b x 16 m-tiles, per-iteration
// shape IDENTICAL to R5's proven loop; halves combined via LDS.
__global__ __launch_bounds__(512, 4)
void k23_fusedE(const unsigned short* __restrict__ Ew, const float* __restrict__ Zpart,
                const unsigned short* __restrict__ seq_bf,
                const unsigned short* __restrict__ phimu, const float* __restrict__ plusT,
                const float* __restrict__ seq, float* __restrict__ out) {
    __shared__ __align__(16) unsigned short e_lds[2][64 * 72];   // E dbuf -> den/num scratch
    __shared__ __align__(16) unsigned short q_lds[256 * 72];     // q tile (36864 B)
    __shared__ float s_plus[NM];
    __shared__ float w_lds[8];                                   // wave BCE partials

    const int t = threadIdx.x;
    const int c = blockIdx.x >> 1;
    const int n = (blockIdx.x & 1) ? (1 + c) : (NM1 - c);        // big/small pairing
    const int ksteps = (n + 63) >> 6;
    const int wv = t >> 6, lane = t & 63, half = lane >> 5, r = lane & 31;

    // stage plus row + Z (ready since launch 1)
    if (t < 256) *(f32x4*)(s_plus + t * 4) = *(const f32x4*)(plusT + (size_t)n * NM + t * 4);
    float Zr0 = 0.f, Zr1 = 0.f;
    for (int kk = 0; kk < ksteps; kk++) {
        const float* zp = Zpart + ((size_t)(n - 1) * 8 + kk) * 64;
        Zr0 += zp[r];
        Zr1 += zp[32 + r];
    }

    // ================= phase 1: hat_phi tile (256 b x 64 h) =================
    const unsigned short* Eb = Ew + (size_t)slab_base(n) * 4096;
    const int eh = t >> 3, ec = (t & 7) * 8;                     // 512-thr E staging map
    const unsigned short* s0 = seq_bf + (size_t)(wv * 32 + r) * NPOS;  // wave owns 32 b

    f32x16 acc0, acc1;
#pragma unroll
    for (int i = 0; i < 16; i++) { acc0[i] = 0.f; acc1[i] = 0.f; }

    bf16x8 er0, en0, sc0[4], sn0[4];
    er0 = *(const bf16x8*)(Eb + eh * 64 + ec);
#pragma unroll
    for (int kq = 0; kq < 4; kq++)
        sc0[kq] = *(const bf16x8*)(s0 + kq * 16 + half * 8);

    for (int kk = 0; kk < ksteps; kk++) {
        unsigned short* ebuf = (unsigned short*)e_lds[kk & 1];
        // 1. stage E tile from regs (one b128 per thread)
        *(bf16x8*)(ebuf + eh * 72 + ec) = er0;
        // 2. prefetch k+1 (stays in flight across the raw barrier)
        if (kk + 1 < ksteps) {
            en0 = *(const bf16x8*)(Eb + (kk + 1) * 4096 + eh * 64 + ec);
            const int k0 = (kk + 1) * 64;
#pragma unroll
            for (int kq = 0; kq < 4; kq++)
                sn0[kq] = *(const bf16x8*)(s0 + k0 + kq * 16 + half * 8);
        }
        // 3. LDS-only fence + raw barrier (global prefetches NOT drained)
        asm volatile("s_waitcnt lgkmcnt(0)" ::: "memory");
        __builtin_amdgcn_s_barrier();
        asm volatile("" ::: "memory");
        // 4. MFMA: D[b][h] += S[b,i] * E[h,i]  (2 independent chains)
        {
            const unsigned short* sB0 = ebuf + r * 72;
            const unsigned short* sB1 = sB0 + 32 * 72;
#pragma unroll
            for (int kq = 0; kq < 4; kq++) {
                const int ko = kq * 16 + half * 8;
                bf16x8 B0 = *(const bf16x8*)(sB0 + ko);
                bf16x8 B1 = *(const bf16x8*)(sB1 + ko);
                acc0 = __builtin_amdgcn_mfma_f32_32x32x16_bf16(sc0[kq], B0, acc0, 0, 0, 0);
                acc1 = __builtin_amdgcn_mfma_f32_32x32x16_bf16(sc0[kq], B1, acc1, 0, 0, 0);
            }
        }
        // 5. rotate fragments
        if (kk + 1 < ksteps) {
            er0 = en0;
#pragma unroll
            for (int kq = 0; kq < 4; kq++) sc0[kq] = sn0[kq];
        }
    }
    // epilogue: scale by 1/Z[h], write q tile (wave-own 32 b rows, stride 72)
    {
        float rz0 = 1.0f / Zr0;
        float rz1 = 1.0f / Zr1;
#pragma unroll
        for (int reg = 0; reg < 16; reg++) {
            int row = (reg & 3) + 8 * (reg >> 2) + 4 * half;
            q_lds[(wv * 32 + row) * 72 + r]      = f2bf(acc0[reg] * rz0);
            q_lds[(wv * 32 + row) * 72 + 32 + r] = f2bf(acc1[reg] * rz1);
        }
    }

    // ================= phase 2: retrieval softmax (m-split) =================
    const int wg = wv & 3;        // b-group: 64 b = wg*64 + {r, 32+r}
    const int mh = wv >> 2;       // m-half: tiles [mh*16, mh*16+16)

    bf16x8 p[4], pn[4];
    p2_load(p, phimu, mh * 16, r, half);   // issue before barrier (hides L2 latency)
    __syncthreads();                        // q tile complete (cross-wave reads)

    bf16x8 q0[4], q1[4];
#pragma unroll
    for (int kq = 0; kq < 4; kq++) {
        q0[kq] = *(const bf16x8*)(q_lds + (wg * 64 + r) * 72 + kq * 16 + half * 8);
        q1[kq] = *(const bf16x8*)(q_lds + (wg * 64 + 32 + r) * 72 + kq * 16 + half * 8);
    }
    f32x16 zacc;
#pragma unroll
    for (int i = 0; i < 16; i++) zacc[i] = 0.f;

    f32x4 den0 = {0.f,0.f,0.f,0.f}, num0 = {0.f,0.f,0.f,0.f};
    f32x4 den1 = {0.f,0.f,0.f,0.f}, num1 = {0.f,0.f,0.f,0.f};
    f32x16 a0, a1;

    for (int it = 0; it < 16; ++it) {
        const int tile = mh * 16 + it;
        if (it < 15) p2_load(pn, phimu, tile + 1, r, half);   // prefetch, no barrier
        a0 = __builtin_amdgcn_mfma_f32_32x32x16_bf16(p[0], q0[0], zacc, 0, 0, 0);
        a1 = __builtin_amdgcn_mfma_f32_32x32x16_bf16(p[0], q1[0], zacc, 0, 0, 0);
#pragma unroll
        for (int kq = 1; kq < 4; kq++) {
            a0 = __builtin_amdgcn_mfma_f32_32x32x16_bf16(p[kq], q0[kq], a0, 0, 0, 0);
            a1 = __builtin_amdgcn_mfma_f32_32x32x16_bf16(p[kq], q1[kq], a1, 0, 0, 0);
        }
        const int mb = tile * 32;
#pragma unroll
        for (int g2 = 0; g2 < 4; g2++) {
            f32x4 pv = *(const f32x4*)(s_plus + mb + 4 * half + 8 * g2);
            f32x4 e0, e1;
#pragma unroll
            for (int j = 0; j < 4; j++) {
                e0[j] = EXP2F(a0[4 * g2 + j]);   // m = mb + j + 8*g2 + 4*half
                e1[j] = EXP2F(a1[4 * g2 + j]);
            }
            den0 += e0; num0 += e0 * pv;
            den1 += e1; num1 += e1 * pv;
        }
        if (it < 15) {
#pragma unroll
            for (int kq = 0; kq < 4; kq++) p[kq] = pn[kq];
        }
    }

    float d0 = (den0[0] + den0[1]) + (den0[2] + den0[3]);
    float nu0 = (num0[0] + num0[1]) + (num0[2] + num0[3]);
    float d1 = (den1[0] + den1[1]) + (den1[2] + den1[3]);
    float nu1 = (num1[0] + num1[1]) + (num1[2] + num1[3]);
    // combine the two intra-tile m-halves (same b)
    d0 += __shfl_xor(d0, 32); nu0 += __shfl_xor(nu0, 32);
    d1 += __shfl_xor(d1, 32); nu1 += __shfl_xor(nu1, 32);

    // cross-wave combine of the two m-halves via LDS (e_lds dead after phase 1)
    float* dsum = (float*)e_lds;          // [2][256]
    float* nsum = dsum + 512;             // [2][256]
    if (half == 0) {
        dsum[mh * 256 + wg * 64 + r]      = d0; nsum[mh * 256 + wg * 64 + r]      = nu0;
        dsum[mh * 256 + wg * 64 + 32 + r] = d1; nsum[mh * 256 + wg * 64 + 32 + r] = nu1;
    }
    __syncthreads();
    // BCE for b = t (t < 256)
    float bce = 0.f;
    if (t < 256) {
        float dd  = dsum[t] + dsum[256 + t];
        float nn2 = nsum[t] + nsum[256 + t];
        float p2 = nn2 / dd;
        p2 = fminf(fmaxf(p2, 1e-6f), 1.0f - 1e-6f);
        float tg = seq[(size_t)t * NPOS + n];
        bce = (tg > 0.f) ? -logf(p2) : -logf(1.0f - p2);
    }
#pragma unroll
    for (int o = 32; o; o >>= 1) bce += __shfl_xor(bce, o);
    if (lane == 0) w_lds[wv] = bce;
    __syncthreads();
    if (t == 0) {
        float s = ((w_lds[0] + w_lds[1]) + (w_lds[2] + w_lds[3]))
                + ((w_lds[4] + w_lds[5]) + (w_lds[6] + w_lds[7]));
        atomicAdd(out, s * (1.0f / 130816.0f));
    }
}

// =====================================================================
// ====== PATH B (small workspace): round-0 kernels, verbatim ==========
// =====================================================================

__global__ __launch_bounds__(256, 4)
void kA_prep(const float* __restrict__ seq, const float* __restrict__ Bl,
             const float* __restrict__ mem,
             unsigned short* __restrict__ seq_bf, float* __restrict__ BnT,
             float* __restrict__ plusT, float* __restrict__ out) {
    const int bid = blockIdx.x, t = threadIdx.x;
    if (bid < 128) {
        if (bid == 0 && t == 0) out[0] = 0.f;
        int idx = (bid * 256 + t) * 4;
        f32x4 v = *(const f32x4*)(seq + idx);
        int2 o;
        o.x = pack2(f2bf(v.x), f2bf(v.y));
        o.y = pack2(f2bf(v.z), f2bf(v.w));
        *(int2*)(seq_bf + idx) = o;
    } else if (bid < 144) {
        const int h = (bid - 128) * 4 + (t >> 6), l = t & 63;
        float v[8]; float mx = -1e30f;
#pragma unroll
        for (int j = 0; j < 8; j++) { v[j] = Bl[h * NPOS + l + 64 * j]; mx = fmaxf(mx, v[j]); }
#pragma unroll
        for (int o = 32; o; o >>= 1) mx = fmaxf(mx, __shfl_xor(mx, o));
        float s = 0.f;
#pragma unroll
        for (int j = 0; j < 8; j++) { v[j] = __expf(v[j] - mx); s += v[j]; }
#pragma unroll
        for (int o = 32; o; o >>= 1) s += __shfl_xor(s, o);
        float r = 1.0f / s;
#pragma unroll
        for (int j = 0; j < 8; j++) BnT[(l + 64 * j) * NH + h] = v[j] * r;
    } else {
        __shared__ float sT[64][65];
        const int bb = bid - 144;
        const int mt = bb >> 3, nt = bb & 7;
        const int rr = t >> 2, cc = t & 3;
        const float* src = mem + (size_t)(mt * 64 + rr) * NPOS + nt * 64 + cc * 16;
#pragma unroll
        for (int j = 0; j < 4; j++) {
            f32x4 v = *(const f32x4*)(src + j * 4);
            sT[rr][cc * 16 + j * 4 + 0] = (v.x > 0.f) ? 1.f : 0.f;
            sT[rr][cc * 16 + j * 4 + 1] = (v.y > 0.f) ? 1.f : 0.f;
            sT[rr][cc * 16 + j * 4 + 2] = (v.z > 0.f) ? 1.f : 0.f;
            sT[rr][cc * 16 + j * 4 + 3] = (v.w > 0.f) ? 1.f : 0.f;
        }
        __syncthreads();
        float* dst = plusT + (size_t)(nt * 64 + rr) * NM + mt * 64 + cc * 16;
#pragma unroll
        for (int j = 0; j < 4; j++) {
            f32x4 o;
            o.x = sT[cc * 16 + j * 4 + 0][rr];
            o.y = sT[cc * 16 + j * 4 + 1][rr];
            o.z = sT[cc * 16 + j * 4 + 2][rr];
            o.w = sT[cc * 16 + j * 4 + 3][rr];
            *(f32x4*)(dst + j * 4) = o;
        }
    }
}

__global__ __launch_bounds__(256, 2)
void k23_fused0(const float* __restrict__ Al, const unsigned short* __restrict__ seq_bf,
                const unsigned short* __restrict__ phimu, const float* __restrict__ plusT,
                const float* __restrict__ seq, float* __restrict__ out) {
    __shared__ __align__(16) unsigned short s_lds[256 * 72];
    __shared__ __align__(16) unsigned short e_lds[64 * 72];
    __shared__ float z_lds[64];
    __shared__ float s_plus[NM];

    const int t = threadIdx.x;
    const int n = NM1 - (int)blockIdx.x;
    const int ksteps = (n + 63) >> 6;
    const int wv = t >> 6, lane = t & 63, half = lane >> 5, r = lane & 31;

    if (t < 64) z_lds[t] = 0.f;
    *(f32x4*)(s_plus + t * 4) = *(const f32x4*)(plusT + n * NM + t * 4);

    const int eh = t >> 2, ei = (t & 3) * 16;
    const float* arow = Al + ((size_t)n * NH + eh) * NPOS + ei;
    const unsigned short* srcS = seq_bf + (size_t)t * NPOS;

    f32x16 acc00, acc01, acc10, acc11;
#pragma unroll
    for (int i = 0; i < 16; i++) { acc00[i] = 0.f; acc01[i] = 0.f; acc10[i] = 0.f; acc11[i] = 0.f; }

    f32x4 ea[4]; i32x4 sa[8];
#pragma unroll
    for (int g = 0; g < 4; g++) ea[g] = *(const f32x4*)(arow + g * 4);
#pragma unroll
    for (int c = 0; c < 8; c++) sa[c] = *(const i32x4*)(srcS + c * 8);
    __syncthreads();

    for (int kk = 0; kk < ksteps; kk++) {
        const int k0 = kk * 64;
        {
            float zp = 0.f;
            unsigned short* ep = e_lds + eh * 72 + ei;
#pragma unroll
            for (int g = 0; g < 4; g++) {
                int i0 = k0 + ei + g * 4;
                float e0 = (i0 + 0 < n) ? __expf(ea[g].x) : 0.f;
                float e1 = (i0 + 1 < n) ? __expf(ea[g].y) : 0.f;
                float e2 = (i0 + 2 < n) ? __expf(ea[g].z) : 0.f;
                float e3 = (i0 + 3 < n) ? __expf(ea[g].w) : 0.f;
                zp += (e0 + e1) + (e2 + e3);
                int2 o; o.x = pack2(f2bf(e0), f2bf(e1)); o.y = pack2(f2bf(e2), f2bf(e3));
                *(int2*)(ep + g * 4) = o;
            }
            zp += __shfl_xor(zp, 1);
            zp += __shfl_xor(zp, 2);
            if ((t & 3) == 0) z_lds[eh] += zp;
        }
        {
            unsigned short* dp = s_lds + t * 72;
#pragma unroll
            for (int c = 0; c < 8; c++) *(i32x4*)(dp + c * 8) = sa[c];
        }
        __syncthreads();
        if (kk + 1 < ksteps) {
#pragma unroll
            for (int g = 0; g < 4; g++) ea[g] = *(const f32x4*)(arow + k0 + 64 + g * 4);
#pragma unroll
            for (int c = 0; c < 8; c++) sa[c] = *(const i32x4*)(srcS + k0 + 64 + c * 8);
        }
        {
            const unsigned short* sA0 = s_lds + (wv * 64 + r) * 72;
            const unsigned short* sA1 = sA0 + 32 * 72;
            const unsigned short* sB0 = e_lds + r * 72;
            const unsigned short* sB1 = sB0 + 32 * 72;
#pragma unroll
            for (int kq = 0; kq < 4; kq++) {
                const int ko = kq * 16 + half * 8;
                bf16x8 A0 = *(const bf16x8*)(sA0 + ko);
                bf16x8 A1 = *(const bf16x8*)(sA1 + ko);
                bf16x8 B0 = *(const bf16x8*)(sB0 + ko);
                bf16x8 B1 = *(const bf16x8*)(sB1 + ko);
                acc00 = __builtin_amdgcn_mfma_f32_32x32x16_bf16(A0, B0, acc00, 0, 0, 0);
                acc01 = __builtin_amdgcn_mfma_f32_32x32x16_bf16(A0, B1, acc01, 0, 0, 0);
                acc10 = __builtin_amdgcn_mfma_f32_32x32x16_bf16(A1, B0, acc10, 0, 0, 0);
                acc11 = __builtin_amdgcn_mfma_f32_32x32x16_bf16(A1, B1, acc11, 0, 0, 0);
            }
        }
        __syncthreads();
    }
    {
        float rz0 = 1.0f / z_lds[r];
        float rz1 = 1.0f / z_lds[32 + r];
#pragma unroll
        for (int reg = 0; reg < 16; reg++) {
            int row = (reg & 3) + 8 * (reg >> 2) + 4 * half;
            s_lds[(wv * 64 + row) * 72 + r]            = f2bf(acc00[reg] * rz0);
            s_lds[(wv * 64 + row) * 72 + 32 + r]       = f2bf(acc01[reg] * rz1);
            s_lds[(wv * 64 + 32 + row) * 72 + r]       = f2bf(acc10[reg] * rz0);
            s_lds[(wv * 64 + 32 + row) * 72 + 32 + r]  = f2bf(acc11[reg] * rz1);
        }
    }
    __syncthreads();

    bf16x8 p[4];
#pragma unroll
    for (int kq = 0; kq < 4; kq++)
        p[kq] = *(const bf16x8*)(phimu + (r) * NH + kq * 16 + half * 8);
    bf16x8 q[2][4];
#pragma unroll
    for (int bs = 0; bs < 2; bs++)
#pragma unroll
        for (int kq = 0; kq < 4; kq++)
            q[bs][kq] = *(const bf16x8*)(s_lds + (wv * 64 + bs * 32 + r) * 72 + kq * 16 + half * 8);

    f32x4 den0 = {0.f,0.f,0.f,0.f}, num0 = {0.f,0.f,0.f,0.f};
    f32x4 den1 = {0.f,0.f,0.f,0.f}, num1 = {0.f,0.f,0.f,0.f};

    for (int it = 0; it < 32; ++it) {
        bf16x8 pn[4];
        if (it < 31) {
#pragma unroll
            for (int kq = 0; kq < 4; kq++)
                pn[kq] = *(const bf16x8*)(phimu + ((it + 1) * 32 + r) * NH + kq * 16 + half * 8);
        }
        f32x16 a0, a1;
#pragma unroll
        for (int i = 0; i < 16; i++) { a0[i] = 0.f; a1[i] = 0.f; }
#pragma unroll
        for (int kq = 0; kq < 4; kq++) {
            a0 = __builtin_amdgcn_mfma_f32_32x32x16_bf16(p[kq], q[0][kq], a0, 0, 0, 0);
            a1 = __builtin_amdgcn_mfma_f32_32x32x16_bf16(p[kq], q[1][kq], a1, 0, 0, 0);
        }
        const int mb = it * 32;
        f32x4 pv[4];
#pragma unroll
        for (int g = 0; g < 4; g++) pv[g] = *(const f32x4*)(s_plus + mb + 4 * half + 8 * g);
#pragma unroll
        for (int g = 0; g < 4; g++) {
            f32x4 e0, e1;
#pragma unroll
            for (int j = 0; j < 4; j++) {
                e0[j] = EXP2F(a0[4 * g + j]);
                e1[j] = EXP2F(a1[4 * g + j]);
            }
            den0 += e0; num0 += e0 * pv[g];
            den1 += e1; num1 += e1 * pv[g];
        }
        if (it < 31) {
#pragma unroll
            for (int kq = 0; kq < 4; kq++) p[kq] = pn[kq];
        }
    }
    float d0 = (den0[0] + den0[1]) + (den0[2] + den0[3]);
    float nu0 = (num0[0] + num0[1]) + (num0[2] + num0[3]);
    float d1 = (den1[0] + den1[1]) + (den1[2] + den1[3]);
    float nu1 = (num1[0] + num1[1]) + (num1[2] + num1[3]);
    d0 += __shfl_xor(d0, 32); nu0 += __shfl_xor(nu0, 32);
    d1 += __shfl_xor(d1, 32); nu1 += __shfl_xor(nu1, 32);

    float* dsum = (float*)e_lds;
    float* nsum = dsum + 256;
    if (half == 0) {
        dsum[wv * 64 + r]      = d0; nsum[wv * 64 + r]      = nu0;
        dsum[wv * 64 + 32 + r] = d1; nsum[wv * 64 + 32 + r] = nu1;
    }
    __syncthreads();
    {
        float dd = dsum[t], nn = nsum[t];
        float p2 = nn / dd;
        p2 = fminf(fmaxf(p2, 1e-6f), 1.0f - 1e-6f);
        float tg = seq[(size_t)t * NPOS + n];
        float bce = (tg > 0.f) ? -logf(p2) : -logf(1.0f - p2);
#pragma unroll
        for (int o = 32; o; o >>= 1) bce += __shfl_xor(bce, o);
        if (lane == 0) z_lds[wv] = bce;
    }
    __syncthreads();
    if (t == 0)
        atomicAdd(out, (z_lds[0] + z_lds[1] + z_lds[2] + z_lds[3]) * (1.0f / 130816.0f));
}

extern "C" void kernel_launch(void* const* d_in, const int* in_sizes, int n_in,
                              void* d_out, int out_size, void* d_ws, size_t ws_size,
                              hipStream_t stream) {
    const float* seq = (const float*)d_in[0];  // (B,N)
    const float* mem = (const float*)d_in[1];  // (M,N)
    const float* Al  = (const float*)d_in[2];  // (N,H,N)
    const float* Bl  = (const float*)d_in[3];  // (H,N)

    char* ws = (char*)d_ws;
    unsigned short* seq_bf = (unsigned short*)(ws + 0);          // 256 KB
    float*          BnT    = (float*)(ws + 262144);              // 128 KB (N,H)
    unsigned short* phimu  = (unsigned short*)(ws + 393216);     // 128 KB (M,H) *log2e
    float*          plusT  = (float*)(ws + 524288);              // 2 MB (N,M)
    float*          Zpart  = (float*)(ws + 2621440);             // 1 MB (N-1,8,64) Z partials
    unsigned short* Ew     = (unsigned short*)(ws + 3670016);    // 18.8 MB exact-slab bf16 E
    float*          outp   = (float*)d_out;

    const size_t WS_NEEDED_E = 3670016 + (size_t)2296 * 8192;    // 22.5 MB (R5 proved available)

    if (ws_size >= WS_NEEDED_E) {
        // PATH A: E-precompute + 8-wave m-split fused kernel
        kAE_prep<<<2568, 256, 0, stream>>>(seq, Bl, mem, Al, seq_bf, BnT, plusT, Ew, Zpart, outp);
        k1b_phimu<<<512, 256, 0, stream>>>(BnT, mem, phimu);
        k23_fusedE<<<511, 512, 0, stream>>>(Ew, Zpart, seq_bf, phimu, plusT, seq, outp);
    } else {
        // PATH B: round-0 proven kernels (145.6 us, absmax 0.0)
        kA_prep<<<272, 256, 0, stream>>>(seq, Bl, mem, seq_bf, BnT, plusT, outp);
        k1b_phimu<<<512, 256, 0, stream>>>(BnT, mem, phimu);
        k23_fused0<<<511, 256, 0, stream>>>(Al, seq_bf, phimu, plusT, seq, outp);
    }
}

// Round 8
// 149.230 us; speedup vs baseline: 1.2282x; 1.0317x over previous
//
#include <hip/hip_runtime.h>
#include <stdint.h>

// Problem constants (fixed by reference setup_inputs)
#define NPOS 512   // N
#define NH   64    // H
#define NM   1024  // M
#define NB   256   // B
#define NM1  511   // N-1

typedef __attribute__((ext_vector_type(8)))  short bf16x8;
typedef __attribute__((ext_vector_type(16))) float f32x16;
typedef __attribute__((ext_vector_type(4)))  float f32x4;
typedef __attribute__((ext_vector_type(4)))  int   i32x4;

#if __has_builtin(__builtin_amdgcn_exp2f)
#define EXP2F(x) __builtin_amdgcn_exp2f(x)
#else
#define EXP2F(x) __expf((x) * 0.69314718055994531f)
#endif

__device__ __forceinline__ unsigned short f2bf(float x) {
    unsigned u = __float_as_uint(x);
    u = (u + 0x7FFFu + ((u >> 16) & 1u)) >> 16;   // RNE
    return (unsigned short)u;
}
__device__ __forceinline__ int pack2(unsigned short a, unsigned short b) {
    return (int)a | ((int)b << 16);
}
// v_cvt_pk_bf16_f32: two f32 -> packed 2x bf16 (low=s0, high=s1)
__device__ __forceinline__ int cvtpk(float lo, float hi) {
    int r;
    asm volatile("v_cvt_pk_bf16_f32 %0, %1, %2" : "=v"(r) : "v"(lo), "v"(hi));
    return r;
}
// slabs before row n (n in 1..511), slab = 64 k-elems
__device__ __forceinline__ int slab_base(int n) {
    int g = (n + 63) >> 6;
    return 32 * (g - 1) * g + (n - 1 - (g - 1) * 64) * g;
}

// =====================================================================
// ============ PATH A (large workspace): E-precompute design ==========
// =====================================================================

// kAE: {k0 seq->bf16 + zero out, k1a BnT softmax, k1c plusT transpose,
//       kE slab-balanced masked-exp of A -> bf16 E + f32 Z partials}.
__global__ __launch_bounds__(256, 4)
void kAE_prep(const float* __restrict__ seq, const float* __restrict__ Bl,
              const float* __restrict__ mem, const float* __restrict__ Al,
              unsigned short* __restrict__ seq_bf, float* __restrict__ BnT,
              float* __restrict__ plusT, unsigned short* __restrict__ Ew,
              float* __restrict__ Zpart, float* __restrict__ out) {
    const int bid = blockIdx.x, t = threadIdx.x;
    if (bid < 128) {
        // --- k0: sequences fp32 -> bf16 (exact for +/-1) ---
        if (bid == 0 && t == 0) out[0] = 0.f;
        int idx = (bid * 256 + t) * 4;
        f32x4 v = *(const f32x4*)(seq + idx);
        int2 o;
        o.x = pack2(f2bf(v.x), f2bf(v.y));
        o.y = pack2(f2bf(v.z), f2bf(v.w));
        *(int2*)(seq_bf + idx) = o;
    } else if (bid < 144) {
        // --- k1a: Bn = softmax(B_logits, axis=-1), stored transposed ---
        const int h = (bid - 128) * 4 + (t >> 6), l = t & 63;
        float v[8]; float mx = -1e30f;
#pragma unroll
        for (int j = 0; j < 8; j++) { v[j] = Bl[h * NPOS + l + 64 * j]; mx = fmaxf(mx, v[j]); }
#pragma unroll
        for (int o = 32; o; o >>= 1) mx = fmaxf(mx, __shfl_xor(mx, o));
        float s = 0.f;
#pragma unroll
        for (int j = 0; j < 8; j++) { v[j] = __expf(v[j] - mx); s += v[j]; }
#pragma unroll
        for (int o = 32; o; o >>= 1) s += __shfl_xor(s, o);
        float r = 1.0f / s;
#pragma unroll
        for (int j = 0; j < 8; j++) BnT[(l + 64 * j) * NH + h] = v[j] * r;
    } else if (bid < 272) {
        // --- k1c: plusT[n][m] via LDS 64x64 tile transpose ---
        __shared__ float sT[64][65];
        const int bb = bid - 144;
        const int mt = bb >> 3, nt = bb & 7;
        const int rr = t >> 2, cc = t & 3;
        const float* src = mem + (size_t)(mt * 64 + rr) * NPOS + nt * 64 + cc * 16;
#pragma unroll
        for (int j = 0; j < 4; j++) {
            f32x4 v = *(const f32x4*)(src + j * 4);
            sT[rr][cc * 16 + j * 4 + 0] = (v.x > 0.f) ? 1.f : 0.f;
            sT[rr][cc * 16 + j * 4 + 1] = (v.y > 0.f) ? 1.f : 0.f;
            sT[rr][cc * 16 + j * 4 + 2] = (v.z > 0.f) ? 1.f : 0.f;
            sT[rr][cc * 16 + j * 4 + 3] = (v.w > 0.f) ? 1.f : 0.f;
        }
        __syncthreads();
        float* dst = plusT + (size_t)(nt * 64 + rr) * NM + mt * 64 + cc * 16;
#pragma unroll
        for (int j = 0; j < 4; j++) {
            f32x4 o;
            o.x = sT[cc * 16 + j * 4 + 0][rr];
            o.y = sT[cc * 16 + j * 4 + 1][rr];
            o.z = sT[cc * 16 + j * 4 + 2][rr];
            o.w = sT[cc * 16 + j * 4 + 3][rr];
            *(f32x4*)(dst + j * 4) = o;
        }
    } else {
        // --- kE slab: sid -> (n, kk). Group g = ceil(n/64). ---
        const int sid = bid - 272;
        int g, Cp;
        if      (sid < 64)   { g = 1; Cp = 0;    }
        else if (sid < 192)  { g = 2; Cp = 64;   }
        else if (sid < 384)  { g = 3; Cp = 192;  }
        else if (sid < 640)  { g = 4; Cp = 384;  }
        else if (sid < 960)  { g = 5; Cp = 640;  }
        else if (sid < 1344) { g = 6; Cp = 960;  }
        else if (sid < 1792) { g = 7; Cp = 1344; }
        else                 { g = 8; Cp = 1792; }
        const int off = sid - Cp;
        const int nIdx = off / g;
        const int kk = off - nIdx * g;
        const int n = (g - 1) * 64 + 1 + nIdx;
        const int sbase = 32 * (g - 1) * g + nIdx * g;      // slab_base(n)

        const int h = t >> 2, j = t & 3;
        const int i0 = kk * 64 + j * 16;
        const float* Ar = Al + ((size_t)n * NH + h) * NPOS + i0;
        unsigned short* Er = Ew + (size_t)(sbase + kk) * 4096 + h * 64 + j * 16;

        f32x4 v0 = *(const f32x4*)(Ar + 0);
        f32x4 v1 = *(const f32x4*)(Ar + 4);
        f32x4 v2 = *(const f32x4*)(Ar + 8);
        f32x4 v3 = *(const f32x4*)(Ar + 12);
        float e[16];
        e[0]  = (i0 + 0  < n) ? __expf(v0.x) : 0.f;
        e[1]  = (i0 + 1  < n) ? __expf(v0.y) : 0.f;
        e[2]  = (i0 + 2  < n) ? __expf(v0.z) : 0.f;
        e[3]  = (i0 + 3  < n) ? __expf(v0.w) : 0.f;
        e[4]  = (i0 + 4  < n) ? __expf(v1.x) : 0.f;
        e[5]  = (i0 + 5  < n) ? __expf(v1.y) : 0.f;
        e[6]  = (i0 + 6  < n) ? __expf(v1.z) : 0.f;
        e[7]  = (i0 + 7  < n) ? __expf(v1.w) : 0.f;
        e[8]  = (i0 + 8  < n) ? __expf(v2.x) : 0.f;
        e[9]  = (i0 + 9  < n) ? __expf(v2.y) : 0.f;
        e[10] = (i0 + 10 < n) ? __expf(v2.z) : 0.f;
        e[11] = (i0 + 11 < n) ? __expf(v2.w) : 0.f;
        e[12] = (i0 + 12 < n) ? __expf(v3.x) : 0.f;
        e[13] = (i0 + 13 < n) ? __expf(v3.y) : 0.f;
        e[14] = (i0 + 14 < n) ? __expf(v3.z) : 0.f;
        e[15] = (i0 + 15 < n) ? __expf(v3.w) : 0.f;
        float zp = 0.f;
#pragma unroll
        for (int q = 0; q < 16; q++) zp += e[q];
        i32x4 w0, w1;
        w0.x = pack2(f2bf(e[0]),  f2bf(e[1]));  w0.y = pack2(f2bf(e[2]),  f2bf(e[3]));
        w0.z = pack2(f2bf(e[4]),  f2bf(e[5]));  w0.w = pack2(f2bf(e[6]),  f2bf(e[7]));
        w1.x = pack2(f2bf(e[8]),  f2bf(e[9]));  w1.y = pack2(f2bf(e[10]), f2bf(e[11]));
        w1.z = pack2(f2bf(e[12]), f2bf(e[13])); w1.w = pack2(f2bf(e[14]), f2bf(e[15]));
        *(i32x4*)(Er)     = w0;
        *(i32x4*)(Er + 8) = w1;
        zp += __shfl_xor(zp, 1);
        zp += __shfl_xor(zp, 2);
        if (j == 0) Zpart[((size_t)(n - 1) * 8 + kk) * 64 + h] = zp;
    }
}

// ---------------- k1b: phi_mu[m,h] -> bf16, BOTH layouts -------------
// 128 blocks x 8 m-rows (4x fewer BnT L2 re-reads than 512x2).
// Writes phimu[m][h] (PATH B) and phimuF (fragment-coalesced, PATH A).
// PRE-SCALED by log2(e).
__global__ __launch_bounds__(256, 4)
void k1b_phimu(const float* __restrict__ BnT, const float* __restrict__ mem,
               unsigned short* __restrict__ phimu, unsigned short* __restrict__ phimuF) {
    const int m0 = blockIdx.x * 8, t = threadIdx.x;
    __shared__ float mrow[8][NPOS];   // 16 KB
    __shared__ float part[8][256];    // 8 KB
#pragma unroll
    for (int ch = 0; ch < 4; ch++) {
        int idx = ch * 256 + t;
        int row = idx >> 7, col = (idx & 127) * 4;
        *(f32x4*)(&mrow[row][col]) = *(const f32x4*)(mem + (size_t)(m0 + row) * NPOS + col);
    }
    __syncthreads();
    const int h = t & 63, seg = t >> 6;
    float a[8], b2[8];
#pragma unroll
    for (int row = 0; row < 8; row++) { a[row] = 0.f; b2[row] = 0.f; }
    const float* bp = BnT + seg * 128 * NH + h;
#pragma unroll 4
    for (int nn = 0; nn < 128; nn += 2) {
        float x0 = bp[nn * NH], x1 = bp[(nn + 1) * NH];
#pragma unroll
        for (int row = 0; row < 8; row++) {
            a[row]  = fmaf(x0, mrow[row][seg * 128 + nn], a[row]);
            b2[row] = fmaf(x1, mrow[row][seg * 128 + nn + 1], b2[row]);
        }
    }
#pragma unroll
    for (int row = 0; row < 8; row++) part[row][t] = a[row] + b2[row];
    __syncthreads();
    if (t < 64) {
#pragma unroll
        for (int row = 0; row < 8; row++) {
            float s = (part[row][t] + part[row][t + 64]) + (part[row][t + 128] + part[row][t + 192]);
            unsigned short v = f2bf(s * 1.4426950408889634f);   // * log2(e)
            const int m = m0 + row;
            phimu[m * NH + t] = v;
            // fragment layout: lane = (m&31) + 32*((h>>3)&1); elem j = h&7; kq = h>>4
            const int tile = m >> 5, rr = m & 31;
            const int kq = t >> 4, hi2 = (t >> 3) & 1, j = t & 7;
            phimuF[(size_t)((tile * 4 + kq) * 64 + rr + 32 * hi2) * 8 + j] = v;
        }
    }
}

// ------------- phase-2 helper: coalesced fragment load -----------------------
// phimuF layout: [(tile*4+kq)*64 + lane][8 bf16] — contiguous 1KB per wave-load.
__device__ __forceinline__ void p2_loadF(bf16x8 (&p)[4], const unsigned short* __restrict__ phimuF,
                                         int tile, int lane) {
#pragma unroll
    for (int kq = 0; kq < 4; kq++)
        p[kq] = *(const bf16x8*)(phimuF + (size_t)((tile * 4 + kq) * 64 + lane) * 8);
}

// ---------------- k23E v3: grid 511, 256 thr = 4 waves (R5 base) -------------
// Phase 1 verbatim from R5 (52.7 us proven). Phase 2 restructured:
//  * coalesced phimuF fragment loads (16 lines/wave-load vs 32 half-used)
//  * den/num via reduce-MFMA: exps -> bf16 (v_cvt_pk_bf16_f32) -> 4 MFMAs/tile
//    against W (col0 = ones, col1 = plus, permuted per A-fragment k-order).
//    Replaces 64 fma + 4 pv ds_reads + final shuffles per iter.
__global__ __launch_bounds__(256, 2)
void k23_fusedE(const unsigned short* __restrict__ Ew, const float* __restrict__ Zpart,
                const unsigned short* __restrict__ seq_bf,
                const unsigned short* __restrict__ phimuF, const float* __restrict__ plusT,
                const float* __restrict__ seq, float* __restrict__ out) {
    __shared__ __align__(16) unsigned short e_lds[2][64 * 72];   // E dbuf -> dsum/nsum scratch
    __shared__ __align__(16) unsigned short q_lds[256 * 72];     // q tile (36864 B)
    __shared__ __align__(16) unsigned short plusbf[32 * 2 * 2 * 8]; // W table: (tile,mm,hi) 8 bf16
    __shared__ float w_lds[4];

    const int t = threadIdx.x;
    const int c0 = blockIdx.x >> 1;
    const int n = (blockIdx.x & 1) ? (1 + c0) : (NM1 - c0);      // big/small pairing
    const int ksteps = (n + 63) >> 6;
    const int wv = t >> 6, lane = t & 63, half = lane >> 5, r = lane & 31;

    // build W table from plusT (global, L2-hot): entry (tile, mm, hi) =
    // plus[n][tile*32 + mm*16 + hi*4 + {0,1,2,3}] ++ [+8..+11]  (sigma k-order)
    if (t < 128) {
        const int tile = t >> 2, mm = (t >> 1) & 1, hh = t & 1;
        const float* src = plusT + (size_t)n * NM + tile * 32 + mm * 16 + hh * 4;
        f32x4 v0 = *(const f32x4*)(src);
        f32x4 v1 = *(const f32x4*)(src + 8);
        unsigned short* dst = plusbf + (size_t)((tile * 2 + mm) * 2 + hh) * 8;
        dst[0] = f2bf(v0.x); dst[1] = f2bf(v0.y); dst[2] = f2bf(v0.z); dst[3] = f2bf(v0.w);
        dst[4] = f2bf(v1.x); dst[5] = f2bf(v1.y); dst[6] = f2bf(v1.z); dst[7] = f2bf(v1.w);
    }
    // Z (sum of per-slab partials; ready since launch 1)
    float Zr0 = 0.f, Zr1 = 0.f;
    for (int kk = 0; kk < ksteps; kk++) {
        const float* zp = Zpart + ((size_t)(n - 1) * 8 + kk) * 64;
        Zr0 += zp[r];
        Zr1 += zp[32 + r];
    }

    // ================= phase 1: hat_phi tile (256 b x 64 h) =================
    const unsigned short* Eb = Ew + (size_t)slab_base(n) * 4096;
    const int eh = t >> 2, ec = (t & 3) * 16;                    // E staging map
    const unsigned short* s0 = seq_bf + (size_t)(wv * 64 + r) * NPOS;
    const unsigned short* s1 = seq_bf + (size_t)(wv * 64 + 32 + r) * NPOS;

    f32x16 acc00, acc01, acc10, acc11;
#pragma unroll
    for (int i = 0; i < 16; i++) { acc00[i] = 0.f; acc01[i] = 0.f; acc10[i] = 0.f; acc11[i] = 0.f; }

    bf16x8 er0, er1, sc0[4], sc1[4], sn0[4], sn1[4];
    er0 = *(const bf16x8*)(Eb + eh * 64 + ec);
    er1 = *(const bf16x8*)(Eb + eh * 64 + ec + 8);
#pragma unroll
    for (int kq = 0; kq < 4; kq++) {
        sc0[kq] = *(const bf16x8*)(s0 + kq * 16 + half * 8);
        sc1[kq] = *(const bf16x8*)(s1 + kq * 16 + half * 8);
    }

    for (int kk = 0; kk < ksteps; kk++) {
        // 1. stage E tile from regs into current buffer
        {
            unsigned short* ep = (unsigned short*)e_lds[kk & 1] + eh * 72 + ec;
            *(bf16x8*)(ep)     = er0;
            *(bf16x8*)(ep + 8) = er1;
        }
        // 2. prefetch k+1 (stays in flight across the raw barrier)
        if (kk + 1 < ksteps) {
            const unsigned short* nb = Eb + (kk + 1) * 4096 + eh * 64 + ec;
            er0 = *(const bf16x8*)(nb);
            er1 = *(const bf16x8*)(nb + 8);
            const int k0 = (kk + 1) * 64;
#pragma unroll
            for (int kq = 0; kq < 4; kq++) {
                sn0[kq] = *(const bf16x8*)(s0 + k0 + kq * 16 + half * 8);
                sn1[kq] = *(const bf16x8*)(s1 + k0 + kq * 16 + half * 8);
            }
        }
        // 3. LDS-only fence + raw barrier (global prefetches NOT drained)
        asm volatile("s_waitcnt lgkmcnt(0)" ::: "memory");
        __builtin_amdgcn_s_barrier();
        asm volatile("" ::: "memory");
        // 4. MFMA: D[b][h] += S[b,i] * E[h,i]
        {
            const unsigned short* sB0 = (const unsigned short*)e_lds[kk & 1] + r * 72;
            const unsigned short* sB1 = sB0 + 32 * 72;
#pragma unroll
            for (int kq = 0; kq < 4; kq++) {
                const int ko = kq * 16 + half * 8;
                bf16x8 B0 = *(const bf16x8*)(sB0 + ko);
                bf16x8 B1 = *(const bf16x8*)(sB1 + ko);
                acc00 = __builtin_amdgcn_mfma_f32_32x32x16_bf16(sc0[kq], B0, acc00, 0, 0, 0);
                acc01 = __builtin_amdgcn_mfma_f32_32x32x16_bf16(sc0[kq], B1, acc01, 0, 0, 0);
                acc10 = __builtin_amdgcn_mfma_f32_32x32x16_bf16(sc1[kq], B0, acc10, 0, 0, 0);
                acc11 = __builtin_amdgcn_mfma_f32_32x32x16_bf16(sc1[kq], B1, acc11, 0, 0, 0);
            }
        }
        // 5. rotate fragments
        if (kk + 1 < ksteps) {
            er0 = er0; er1 = er1;   // (kept; real rotate below)
#pragma unroll
            for (int kq = 0; kq < 4; kq++) { sc0[kq] = sn0[kq]; sc1[kq] = sn1[kq]; }
        }
    }
    // epilogue: scale by 1/Z[h], write q tile into q_lds (wave-own rows).
    {
        float rz0 = 1.0f / Zr0;
        float rz1 = 1.0f / Zr1;
#pragma unroll
        for (int reg = 0; reg < 16; reg++) {
            int row = (reg & 3) + 8 * (reg >> 2) + 4 * half;
            q_lds[(wv * 64 + row) * 72 + r]            = f2bf(acc00[reg] * rz0);
            q_lds[(wv * 64 + row) * 72 + 32 + r]       = f2bf(acc01[reg] * rz1);
            q_lds[(wv * 64 + 32 + row) * 72 + r]       = f2bf(acc10[reg] * rz0);
            q_lds[(wv * 64 + 32 + row) * 72 + 32 + r]  = f2bf(acc11[reg] * rz1);
        }
    }

    // ================= phase 2: retrieval softmax (MFMA-reduced) ============
    bf16x8 p[4], pn[4];
    p2_loadF(p, phimuF, 0, lane);              // coalesced; issue first
    bf16x8 q0[4], q1[4];
#pragma unroll
    for (int kq = 0; kq < 4; kq++) {
        q0[kq] = *(const bf16x8*)(q_lds + (wv * 64 + r) * 72 + kq * 16 + half * 8);
        q1[kq] = *(const bf16x8*)(q_lds + (wv * 64 + 32 + r) * 72 + kq * 16 + half * 8);
    }
    f32x16 zacc, accD0, accD1;
#pragma unroll
    for (int i = 0; i < 16; i++) { zacc[i] = 0.f; accD0[i] = 0.f; accD1[i] = 0.f; }

    // per-lane W-column constants: col 0 = ones, col 1 = plus, others 0
    const unsigned onespat = (r == 0) ? 0x3F803F80u : 0u;
    const unsigned pmask   = (r == 1) ? 0xFFFFFFFFu : 0u;

    for (int it = 0; it < 32; ++it) {
        if (it < 31) p2_loadF(pn, phimuF, it + 1, lane);   // prefetch, no barrier
        // score MFMAs: a0 (b 0..31), a1 (b 32..63)
        f32x16 a0, a1;
        a0 = __builtin_amdgcn_mfma_f32_32x32x16_bf16(p[0], q0[0], zacc, 0, 0, 0);
        a1 = __builtin_amdgcn_mfma_f32_32x32x16_bf16(p[0], q1[0], zacc, 0, 0, 0);
#pragma unroll
        for (int kq = 1; kq < 4; kq++) {
            a0 = __builtin_amdgcn_mfma_f32_32x32x16_bf16(p[kq], q0[kq], a0, 0, 0, 0);
            a1 = __builtin_amdgcn_mfma_f32_32x32x16_bf16(p[kq], q1[kq], a1, 0, 0, 0);
        }
        // W fragments for this tile (broadcast LDS reads; k-order = sigma)
        i32x4 w1r = *(const i32x4*)(plusbf + (size_t)(4 * it + half) * 8);
        i32x4 w2r = *(const i32x4*)(plusbf + (size_t)(4 * it + 2 + half) * 8);
        i32x4 W1, W2;
        W1.x = onespat | (w1r.x & pmask); W1.y = onespat | (w1r.y & pmask);
        W1.z = onespat | (w1r.z & pmask); W1.w = onespat | (w1r.w & pmask);
        W2.x = onespat | (w2r.x & pmask); W2.y = onespat | (w2r.y & pmask);
        W2.z = onespat | (w2r.z & pmask); W2.w = onespat | (w2r.w & pmask);
        // exp -> bf16 A-fragments, reduce-MFMA into accD (col0=den, col1=num)
        {
            float e00 = EXP2F(a0[0]),  e01 = EXP2F(a0[1]),  e02 = EXP2F(a0[2]),  e03 = EXP2F(a0[3]);
            float e04 = EXP2F(a0[4]),  e05 = EXP2F(a0[5]),  e06 = EXP2F(a0[6]),  e07 = EXP2F(a0[7]);
            float e08 = EXP2F(a0[8]),  e09 = EXP2F(a0[9]),  e10 = EXP2F(a0[10]), e11 = EXP2F(a0[11]);
            float e12 = EXP2F(a0[12]), e13 = EXP2F(a0[13]), e14 = EXP2F(a0[14]), e15 = EXP2F(a0[15]);
            i32x4 A1, A2;
            A1.x = cvtpk(e00, e01); A1.y = cvtpk(e02, e03); A1.z = cvtpk(e04, e05); A1.w = cvtpk(e06, e07);
            A2.x = cvtpk(e08, e09); A2.y = cvtpk(e10, e11); A2.z = cvtpk(e12, e13); A2.w = cvtpk(e14, e15);
            accD0 = __builtin_amdgcn_mfma_f32_32x32x16_bf16(*(bf16x8*)&A1, *(bf16x8*)&W1, accD0, 0, 0, 0);
            accD0 = __builtin_amdgcn_mfma_f32_32x32x16_bf16(*(bf16x8*)&A2, *(bf16x8*)&W2, accD0, 0, 0, 0);
        }
        {
            float e00 = EXP2F(a1[0]),  e01 = EXP2F(a1[1]),  e02 = EXP2F(a1[2]),  e03 = EXP2F(a1[3]);
            float e04 = EXP2F(a1[4]),  e05 = EXP2F(a1[5]),  e06 = EXP2F(a1[6]),  e07 = EXP2F(a1[7]);
            float e08 = EXP2F(a1[8]),  e09 = EXP2F(a1[9]),  e10 = EXP2F(a1[10]), e11 = EXP2F(a1[11]);
            float e12 = EXP2F(a1[12]), e13 = EXP2F(a1[13]), e14 = EXP2F(a1[14]), e15 = EXP2F(a1[15]);
            i32x4 A1, A2;
            A1.x = cvtpk(e00, e01); A1.y = cvtpk(e02, e03); A1.z = cvtpk(e04, e05); A1.w = cvtpk(e06, e07);
            A2.x = cvtpk(e08, e09); A2.y = cvtpk(e10, e11); A2.z = cvtpk(e12, e13); A2.w = cvtpk(e14, e15);
            accD1 = __builtin_amdgcn_mfma_f32_32x32x16_bf16(*(bf16x8*)&A1, *(bf16x8*)&W1, accD1, 0, 0, 0);
            accD1 = __builtin_amdgcn_mfma_f32_32x32x16_bf16(*(bf16x8*)&A2, *(bf16x8*)&W2, accD1, 0, 0, 0);
        }
        if (it < 31) {
#pragma unroll
            for (int kq = 0; kq < 4; kq++) p[kq] = pn[kq];
        }
    }

    // accD layout: lane (col=r) 0 holds den[b=rowmap], lane 1 holds num.
    float* dsum = (float*)e_lds;          // 256 floats (e_lds dead after phase 1)
    float* nsum = dsum + 256;
    if (r < 2) {
        float* dst = (r == 0) ? dsum : nsum;
#pragma unroll
        for (int reg = 0; reg < 16; reg++) {
            int row = (reg & 3) + 8 * (reg >> 2) + 4 * half;
            dst[wv * 64 + row]      = accD0[reg];
            dst[wv * 64 + 32 + row] = accD1[reg];
        }
    }
    __syncthreads();
    // BCE for b = t (den/num complete over all m)
    {
        float dd = dsum[t], nn = nsum[t];
        float p2 = nn / dd;
        p2 = fminf(fmaxf(p2, 1e-6f), 1.0f - 1e-6f);
        float tg = seq[(size_t)t * NPOS + n];
        float bce = (tg > 0.f) ? -logf(p2) : -logf(1.0f - p2);
#pragma unroll
        for (int o = 32; o; o >>= 1) bce += __shfl_xor(bce, o);
        if (lane == 0) w_lds[wv] = bce;
    }
    __syncthreads();
    if (t == 0)
        atomicAdd(out, (w_lds[0] + w_lds[1] + w_lds[2] + w_lds[3]) * (1.0f / 130816.0f));
}

// =====================================================================
// ====== PATH B (small workspace): round-0 kernels, verbatim ==========
// =====================================================================

__global__ __launch_bounds__(256, 4)
void kA_prep(const float* __restrict__ seq, const float* __restrict__ Bl,
             const float* __restrict__ mem,
             unsigned short* __restrict__ seq_bf, float* __restrict__ BnT,
             float* __restrict__ plusT, float* __restrict__ out) {
    const int bid = blockIdx.x, t = threadIdx.x;
    if (bid < 128) {
        if (bid == 0 && t == 0) out[0] = 0.f;
        int idx = (bid * 256 + t) * 4;
        f32x4 v = *(const f32x4*)(seq + idx);
        int2 o;
        o.x = pack2(f2bf(v.x), f2bf(v.y));
        o.y = pack2(f2bf(v.z), f2bf(v.w));
        *(int2*)(seq_bf + idx) = o;
    } else if (bid < 144) {
        const int h = (bid - 128) * 4 + (t >> 6), l = t & 63;
        float v[8]; float mx = -1e30f;
#pragma unroll
        for (int j = 0; j < 8; j++) { v[j] = Bl[h * NPOS + l + 64 * j]; mx = fmaxf(mx, v[j]); }
#pragma unroll
        for (int o = 32; o; o >>= 1) mx = fmaxf(mx, __shfl_xor(mx, o));
        float s = 0.f;
#pragma unroll
        for (int j = 0; j < 8; j++) { v[j] = __expf(v[j] - mx); s += v[j]; }
#pragma unroll
        for (int o = 32; o; o >>= 1) s += __shfl_xor(s, o);
        float r = 1.0f / s;
#pragma unroll
        for (int j = 0; j < 8; j++) BnT[(l + 64 * j) * NH + h] = v[j] * r;
    } else {
        __shared__ float sT[64][65];
        const int bb = bid - 144;
        const int mt = bb >> 3, nt = bb & 7;
        const int rr = t >> 2, cc = t & 3;
        const float* src = mem + (size_t)(mt * 64 + rr) * NPOS + nt * 64 + cc * 16;
#pragma unroll
        for (int j = 0; j < 4; j++) {
            f32x4 v = *(const f32x4*)(src + j * 4);
            sT[rr][cc * 16 + j * 4 + 0] = (v.x > 0.f) ? 1.f : 0.f;
            sT[rr][cc * 16 + j * 4 + 1] = (v.y > 0.f) ? 1.f : 0.f;
            sT[rr][cc * 16 + j * 4 + 2] = (v.z > 0.f) ? 1.f : 0.f;
            sT[rr][cc * 16 + j * 4 + 3] = (v.w > 0.f) ? 1.f : 0.f;
        }
        __syncthreads();
        float* dst = plusT + (size_t)(nt * 64 + rr) * NM + mt * 64 + cc * 16;
#pragma unroll
        for (int j = 0; j < 4; j++) {
            f32x4 o;
            o.x = sT[cc * 16 + j * 4 + 0][rr];
            o.y = sT[cc * 16 + j * 4 + 1][rr];
            o.z = sT[cc * 16 + j * 4 + 2][rr];
            o.w = sT[cc * 16 + j * 4 + 3][rr];
            *(f32x4*)(dst + j * 4) = o;
        }
    }
}

__global__ __launch_bounds__(256, 2)
void k23_fused0(const float* __restrict__ Al, const unsigned short* __restrict__ seq_bf,
                const unsigned short* __restrict__ phimu, const float* __restrict__ plusT,
                const float* __restrict__ seq, float* __restrict__ out) {
    __shared__ __align__(16) unsigned short s_lds[256 * 72];
    __shared__ __align__(16) unsigned short e_lds[64 * 72];
    __shared__ float z_lds[64];
    __shared__ float s_plus[NM];

    const int t = threadIdx.x;
    const int n = NM1 - (int)blockIdx.x;
    const int ksteps = (n + 63) >> 6;
    const int wv = t >> 6, lane = t & 63, half = lane >> 5, r = lane & 31;

    if (t < 64) z_lds[t] = 0.f;
    *(f32x4*)(s_plus + t * 4) = *(const f32x4*)(plusT + n * NM + t * 4);

    const int eh = t >> 2, ei = (t & 3) * 16;
    const float* arow = Al + ((size_t)n * NH + eh) * NPOS + ei;
    const unsigned short* srcS = seq_bf + (size_t)t * NPOS;

    f32x16 acc00, acc01, acc10, acc11;
#pragma unroll
    for (int i = 0; i < 16; i++) { acc00[i] = 0.f; acc01[i] = 0.f; acc10[i] = 0.f; acc11[i] = 0.f; }

    f32x4 ea[4]; i32x4 sa[8];
#pragma unroll
    for (int g = 0; g < 4; g++) ea[g] = *(const f32x4*)(arow + g * 4);
#pragma unroll
    for (int c = 0; c < 8; c++) sa[c] = *(const i32x4*)(srcS + c * 8);
    __syncthreads();

    for (int kk = 0; kk < ksteps; kk++) {
        const int k0 = kk * 64;
        {
            float zp = 0.f;
            unsigned short* ep = e_lds + eh * 72 + ei;
#pragma unroll
            for (int g = 0; g < 4; g++) {
                int i0 = k0 + ei + g * 4;
                float e0 = (i0 + 0 < n) ? __expf(ea[g].x) : 0.f;
                float e1 = (i0 + 1 < n) ? __expf(ea[g].y) : 0.f;
                float e2 = (i0 + 2 < n) ? __expf(ea[g].z) : 0.f;
                float e3 = (i0 + 3 < n) ? __expf(ea[g].w) : 0.f;
                zp += (e0 + e1) + (e2 + e3);
                int2 o; o.x = pack2(f2bf(e0), f2bf(e1)); o.y = pack2(f2bf(e2), f2bf(e3));
                *(int2*)(ep + g * 4) = o;
            }
            zp += __shfl_xor(zp, 1);
            zp += __shfl_xor(zp, 2);
            if ((t & 3) == 0) z_lds[eh] += zp;
        }
        {
            unsigned short* dp = s_lds + t * 72;
#pragma unroll
            for (int c = 0; c < 8; c++) *(i32x4*)(dp + c * 8) = sa[c];
        }
        __syncthreads();
        if (kk + 1 < ksteps) {
#pragma unroll
            for (int g = 0; g < 4; g++) ea[g] = *(const f32x4*)(arow + k0 + 64 + g * 4);
#pragma unroll
            for (int c = 0; c < 8; c++) sa[c] = *(const i32x4*)(srcS + k0 + 64 + c * 8);
        }
        {
            const unsigned short* sA0 = s_lds + (wv * 64 + r) * 72;
            const unsigned short* sA1 = sA0 + 32 * 72;
            const unsigned short* sB0 = e_lds + r * 72;
            const unsigned short* sB1 = sB0 + 32 * 72;
#pragma unroll
            for (int kq = 0; kq < 4; kq++) {
                const int ko = kq * 16 + half * 8;
                bf16x8 A0 = *(const bf16x8*)(sA0 + ko);
                bf16x8 A1 = *(const bf16x8*)(sA1 + ko);
                bf16x8 B0 = *(const bf16x8*)(sB0 + ko);
                bf16x8 B1 = *(const bf16x8*)(sB1 + ko);
                acc00 = __builtin_amdgcn_mfma_f32_32x32x16_bf16(A0, B0, acc00, 0, 0, 0);
                acc01 = __builtin_amdgcn_mfma_f32_32x32x16_bf16(A0, B1, acc01, 0, 0, 0);
                acc10 = __builtin_amdgcn_mfma_f32_32x32x16_bf16(A1, B0, acc10, 0, 0, 0);
                acc11 = __builtin_amdgcn_mfma_f32_32x32x16_bf16(A1, B1, acc11, 0, 0, 0);
            }
        }
        __syncthreads();
    }
    {
        float rz0 = 1.0f / z_lds[r];
        float rz1 = 1.0f / z_lds[32 + r];
#pragma unroll
        for (int reg = 0; reg < 16; reg++) {
            int row = (reg & 3) + 8 * (reg >> 2) + 4 * half;
            s_lds[(wv * 64 + row) * 72 + r]            = f2bf(acc00[reg] * rz0);
            s_lds[(wv * 64 + row) * 72 + 32 + r]       = f2bf(acc01[reg] * rz1);
            s_lds[(wv * 64 + 32 + row) * 72 + r]       = f2bf(acc10[reg] * rz0);
            s_lds[(wv * 64 + 32 + row) * 72 + 32 + r]  = f2bf(acc11[reg] * rz1);
        }
    }
    __syncthreads();

    bf16x8 p[4];
#pragma unroll
    for (int kq = 0; kq < 4; kq++)
        p[kq] = *(const bf16x8*)(phimu + (r) * NH + kq * 16 + half * 8);
    bf16x8 q[2][4];
#pragma unroll
    for (int bs = 0; bs < 2; bs++)
#pragma unroll
        for (int kq = 0; kq < 4; kq++)
            q[bs][kq] = *(const bf16x8*)(s_lds + (wv * 64 + bs * 32 + r) * 72 + kq * 16 + half * 8);

    f32x4 den0 = {0.f,0.f,0.f,0.f}, num0 = {0.f,0.f,0.f,0.f};
    f32x4 den1 = {0.f,0.f,0.f,0.f}, num1 = {0.f,0.f,0.f,0.f};

    for (int it = 0; it < 32; ++it) {
        bf16x8 pn[4];
        if (it < 31) {
#pragma unroll
            for (int kq = 0; kq < 4; kq++)
                pn[kq] = *(const bf16x8*)(phimu + ((it + 1) * 32 + r) * NH + kq * 16 + half * 8);
        }
        f32x16 a0, a1;
#pragma unroll
        for (int i = 0; i < 16; i++) { a0[i] = 0.f; a1[i] = 0.f; }
#pragma unroll
        for (int kq = 0; kq < 4; kq++) {
            a0 = __builtin_amdgcn_mfma_f32_32x32x16_bf16(p[kq], q[0][kq], a0, 0, 0, 0);
            a1 = __builtin_amdgcn_mfma_f32_32x32x16_bf16(p[kq], q[1][kq], a1, 0, 0, 0);
        }
        const int mb = it * 32;
        f32x4 pv[4];
#pragma unroll
        for (int g = 0; g < 4; g++) pv[g] = *(const f32x4*)(s_plus + mb + 4 * half + 8 * g);
#pragma unroll
        for (int g = 0; g < 4; g++) {
            f32x4 e0, e1;
#pragma unroll
            for (int j = 0; j < 4; j++) {
                e0[j] = EXP2F(a0[4 * g + j]);
                e1[j] = EXP2F(a1[4 * g + j]);
            }
            den0 += e0; num0 += e0 * pv[g];
            den1 += e1; num1 += e1 * pv[g];
        }
        if (it < 31) {
#pragma unroll
            for (int kq = 0; kq < 4; kq++) p[kq] = pn[kq];
        }
    }
    float d0 = (den0[0] + den0[1]) + (den0[2] + den0[3]);
    float nu0 = (num0[0] + num0[1]) + (num0[2] + num0[3]);
    float d1 = (den1[0] + den1[1]) + (den1[2] + den1[3]);
    float nu1 = (num1[0] + num1[1]) + (num1[2] + num1[3]);
    d0 += __shfl_xor(d0, 32); nu0 += __shfl_xor(nu0, 32);
    d1 += __shfl_xor(d1, 32); nu1 += __shfl_xor(nu1, 32);

    float* dsum = (float*)e_lds;
    float* nsum = dsum + 256;
    if (half == 0) {
        dsum[wv * 64 + r]      = d0; nsum[wv * 64 + r]      = nu0;
        dsum[wv * 64 + 32 + r] = d1; nsum[wv * 64 + 32 + r] = nu1;
    }
    __syncthreads();
    {
        float dd = dsum[t], nn = nsum[t];
        float p2 = nn / dd;
        p2 = fminf(fmaxf(p2, 1e-6f), 1.0f - 1e-6f);
        float tg = seq[(size_t)t * NPOS + n];
        float bce = (tg > 0.f) ? -logf(p2) : -logf(1.0f - p2);
#pragma unroll
        for (int o = 32; o; o >>= 1) bce += __shfl_xor(bce, o);
        if (lane == 0) z_lds[wv] = bce;
    }
    __syncthreads();
    if (t == 0)
        atomicAdd(out, (z_lds[0] + z_lds[1] + z_lds[2] + z_lds[3]) * (1.0f / 130816.0f));
}

extern "C" void kernel_launch(void* const* d_in, const int* in_sizes, int n_in,
                              void* d_out, int out_size, void* d_ws, size_t ws_size,
                              hipStream_t stream) {
    const float* seq = (const float*)d_in[0];  // (B,N)
    const float* mem = (const float*)d_in[1];  // (M,N)
    const float* Al  = (const float*)d_in[2];  // (N,H,N)
    const float* Bl  = (const float*)d_in[3];  // (H,N)

    char* ws = (char*)d_ws;
    unsigned short* seq_bf = (unsigned short*)(ws + 0);          // 256 KB
    float*          BnT    = (float*)(ws + 262144);              // 128 KB (N,H)
    unsigned short* phimu  = (unsigned short*)(ws + 393216);     // 128 KB (M,H) *log2e
    float*          plusT  = (float*)(ws + 524288);              // 2 MB (N,M)
    float*          Zpart  = (float*)(ws + 2621440);             // 1 MB (N-1,8,64) Z partials
    unsigned short* Ew     = (unsigned short*)(ws + 3670016);    // 18.8 MB exact-slab bf16 E
    unsigned short* phimuF = (unsigned short*)(ws + 22478848);   // 128 KB fragment layout
    float*          outp   = (float*)d_out;

    const size_t WS_NEEDED_E = 22478848 + 131072;                // 22.6 MB (R5 proved >=36 MB)

    if (ws_size >= WS_NEEDED_E) {
        // PATH A: E-precompute + MFMA-reduced phase-2 fused kernel
        kAE_prep<<<2568, 256, 0, stream>>>(seq, Bl, mem, Al, seq_bf, BnT, plusT, Ew, Zpart, outp);
        k1b_phimu<<<128, 256, 0, stream>>>(BnT, mem, phimu, phimuF);
        k23_fusedE<<<511, 256, 0, stream>>>(Ew, Zpart, seq_bf, phimuF, plusT, seq, outp);
    } else {
        // PATH B: round-0 proven kernels (145.6 us, absmax 0.0)
        kA_prep<<<272, 256, 0, stream>>>(seq, Bl, mem, seq_bf, BnT, plusT, outp);
        k1b_phimu<<<128, 256, 0, stream>>>(BnT, mem, phimu, phimuF);
        k23_fused0<<<511, 256, 0, stream>>>(Al, seq_bf, phimu, plusT, seq, outp);
    }
}

// Round 9
// 142.081 us; speedup vs baseline: 1.2900x; 1.0503x over previous
//
#include <hip/hip_runtime.h>
#include <stdint.h>

// Problem constants (fixed by reference setup_inputs)
#define NPOS 512   // N
#define NH   64    // H
#define NM   1024  // M
#define NB   256   // B
#define NM1  511   // N-1

typedef __attribute__((ext_vector_type(8)))  short bf16x8;
typedef __attribute__((ext_vector_type(16))) float f32x16;
typedef __attribute__((ext_vector_type(4)))  float f32x4;
typedef __attribute__((ext_vector_type(4)))  int   i32x4;

#if __has_builtin(__builtin_amdgcn_exp2f)
#define EXP2F(x) __builtin_amdgcn_exp2f(x)
#else
#define EXP2F(x) __expf((x) * 0.69314718055994531f)
#endif

__device__ __forceinline__ unsigned short f2bf(float x) {
    unsigned u = __float_as_uint(x);
    u = (u + 0x7FFFu + ((u >> 16) & 1u)) >> 16;   // RNE
    return (unsigned short)u;
}
__device__ __forceinline__ int pack2(unsigned short a, unsigned short b) {
    return (int)a | ((int)b << 16);
}
// v_cvt_pk_bf16_f32: two f32 -> packed 2x bf16 (low=s0, high=s1)
__device__ __forceinline__ int cvtpk(float lo, float hi) {
    int r;
    asm volatile("v_cvt_pk_bf16_f32 %0, %1, %2" : "=v"(r) : "v"(lo), "v"(hi));
    return r;
}

// ---------------- kA: fused prep = {k0 seq->bf16 + zero out, k1a BnT softmax,
//                  k1c plusT transpose}. 272 blocks x 256 thr. (R0, proven) ---
__global__ __launch_bounds__(256, 4)
void kA_prep(const float* __restrict__ seq, const float* __restrict__ Bl,
             const float* __restrict__ mem,
             unsigned short* __restrict__ seq_bf, float* __restrict__ BnT,
             float* __restrict__ plusT, float* __restrict__ out) {
    const int bid = blockIdx.x, t = threadIdx.x;
    if (bid < 128) {
        // --- k0: sequences fp32 -> bf16 (exact for +/-1) ---
        if (bid == 0 && t == 0) out[0] = 0.f;
        int idx = (bid * 256 + t) * 4;
        f32x4 v = *(const f32x4*)(seq + idx);
        int2 o;
        o.x = pack2(f2bf(v.x), f2bf(v.y));
        o.y = pack2(f2bf(v.z), f2bf(v.w));
        *(int2*)(seq_bf + idx) = o;
    } else if (bid < 144) {
        // --- k1a: Bn = softmax(B_logits, axis=-1), stored transposed ---
        const int h = (bid - 128) * 4 + (t >> 6), l = t & 63;
        float v[8]; float mx = -1e30f;
#pragma unroll
        for (int j = 0; j < 8; j++) { v[j] = Bl[h * NPOS + l + 64 * j]; mx = fmaxf(mx, v[j]); }
#pragma unroll
        for (int o = 32; o; o >>= 1) mx = fmaxf(mx, __shfl_xor(mx, o));
        float s = 0.f;
#pragma unroll
        for (int j = 0; j < 8; j++) { v[j] = __expf(v[j] - mx); s += v[j]; }
#pragma unroll
        for (int o = 32; o; o >>= 1) s += __shfl_xor(s, o);
        float r = 1.0f / s;
#pragma unroll
        for (int j = 0; j < 8; j++) BnT[(l + 64 * j) * NH + h] = v[j] * r;
    } else {
        // --- k1c: plusT[n][m] via LDS 64x64 tile transpose ---
        __shared__ float sT[64][65];
        const int bb = bid - 144;
        const int mt = bb >> 3, nt = bb & 7;
        const int rr = t >> 2, cc = t & 3;
        const float* src = mem + (size_t)(mt * 64 + rr) * NPOS + nt * 64 + cc * 16;
#pragma unroll
        for (int j = 0; j < 4; j++) {
            f32x4 v = *(const f32x4*)(src + j * 4);
            sT[rr][cc * 16 + j * 4 + 0] = (v.x > 0.f) ? 1.f : 0.f;
            sT[rr][cc * 16 + j * 4 + 1] = (v.y > 0.f) ? 1.f : 0.f;
            sT[rr][cc * 16 + j * 4 + 2] = (v.z > 0.f) ? 1.f : 0.f;
            sT[rr][cc * 16 + j * 4 + 3] = (v.w > 0.f) ? 1.f : 0.f;
        }
        __syncthreads();
        float* dst = plusT + (size_t)(nt * 64 + rr) * NM + mt * 64 + cc * 16;
#pragma unroll
        for (int j = 0; j < 4; j++) {
            f32x4 o;
            o.x = sT[cc * 16 + j * 4 + 0][rr];
            o.y = sT[cc * 16 + j * 4 + 1][rr];
            o.z = sT[cc * 16 + j * 4 + 2][rr];
            o.w = sT[cc * 16 + j * 4 + 3][rr];
            *(f32x4*)(dst + j * 4) = o;
        }
    }
}

// ---------------- k1b: phi_mu[m,h] -> bf16 FRAGMENT layout only --------------
// 128 blocks x 8 m-rows. PRE-SCALED by log2(e).
// phimuF layout: [(tile*4+kq)*64 + (m&31) + 32*((h>>3)&1)][h&7] — one
// contiguous 1KB line per wave MFMA-A-fragment load.
__global__ __launch_bounds__(256, 4)
void k1b_phimu(const float* __restrict__ BnT, const float* __restrict__ mem,
               unsigned short* __restrict__ phimuF) {
    const int m0 = blockIdx.x * 8, t = threadIdx.x;
    __shared__ float mrow[8][NPOS];   // 16 KB
    __shared__ float part[8][256];    // 8 KB
#pragma unroll
    for (int ch = 0; ch < 4; ch++) {
        int idx = ch * 256 + t;
        int row = idx >> 7, col = (idx & 127) * 4;
        *(f32x4*)(&mrow[row][col]) = *(const f32x4*)(mem + (size_t)(m0 + row) * NPOS + col);
    }
    __syncthreads();
    const int h = t & 63, seg = t >> 6;
    float a[8], b2[8];
#pragma unroll
    for (int row = 0; row < 8; row++) { a[row] = 0.f; b2[row] = 0.f; }
    const float* bp = BnT + seg * 128 * NH + h;
#pragma unroll 4
    for (int nn = 0; nn < 128; nn += 2) {
        float x0 = bp[nn * NH], x1 = bp[(nn + 1) * NH];
#pragma unroll
        for (int row = 0; row < 8; row++) {
            a[row]  = fmaf(x0, mrow[row][seg * 128 + nn], a[row]);
            b2[row] = fmaf(x1, mrow[row][seg * 128 + nn + 1], b2[row]);
        }
    }
#pragma unroll
    for (int row = 0; row < 8; row++) part[row][t] = a[row] + b2[row];
    __syncthreads();
    if (t < 64) {
#pragma unroll
        for (int row = 0; row < 8; row++) {
            float s = (part[row][t] + part[row][t + 64]) + (part[row][t + 128] + part[row][t + 192]);
            unsigned short v = f2bf(s * 1.4426950408889634f);   // * log2(e)
            const int m = m0 + row;
            const int tile = m >> 5, rr = m & 31;
            const int kq = t >> 4, hi2 = (t >> 3) & 1, j = t & 7;
            phimuF[(size_t)((tile * 4 + kq) * 64 + rr + 32 * hi2) * 8 + j] = v;
        }
    }
}

// ------------- phase-2 helper: coalesced fragment load (R8, proven) ----------
__device__ __forceinline__ void p2_loadF(bf16x8 (&p)[4], const unsigned short* __restrict__ phimuF,
                                         int tile, int lane) {
#pragma unroll
    for (int kq = 0; kq < 4; kq++)
        p[kq] = *(const bf16x8*)(phimuF + (size_t)((tile * 4 + kq) * 64 + lane) * 8);
}

// ---------------- k23: FUSED hat_phi + retrieval softmax + BCE ---------------
// grid 511, 256 thr = 4 waves.
// Phase 1 = R3 structure (proven): A fp32 rows + in-kernel masked exp -> E
//   double-buffered in LDS; S-fragments DIRECT from global; ONE raw s_barrier
//   per k-step (lgkmcnt(0) only — global prefetches stay in flight).
// Phase 2 = R8 structure (proven, -9.6us): coalesced phimuF loads; den/num via
//   reduce-MFMA (exp -> v_cvt_pk_bf16_f32 -> 2 MFMAs/chain/tile against W with
//   col0 = ones, col1 = plus).
__global__ __launch_bounds__(256, 2)
void k23_fused(const float* __restrict__ Al, const unsigned short* __restrict__ seq_bf,
               const unsigned short* __restrict__ phimuF, const float* __restrict__ plusT,
               const float* __restrict__ seq, float* __restrict__ out) {
    __shared__ __align__(16) unsigned short e_lds[2][64 * 72];   // E dbuf -> dsum/nsum scratch
    __shared__ __align__(16) unsigned short q_lds[256 * 72];     // q tile (36864 B)
    __shared__ __align__(16) unsigned short plusbf[32 * 2 * 2 * 8]; // W table (2 KB)
    __shared__ float z_lds[64];                                  // row sums Z[h]
    __shared__ float w_lds[4];

    const int t = threadIdx.x;
    const int n = NM1 - (int)blockIdx.x;          // n in 1..511, big n first
    const int ksteps = (n + 63) >> 6;
    const int wv = t >> 6, lane = t & 63, half = lane >> 5, r = lane & 31;

    if (t < 64) z_lds[t] = 0.f;
    // W table from plusT: entry (tile, mm, hh) = plus[n][tile*32+mm*16+hh*4 +
    // {0..3}] ++ [+8..+11] (k-order sigma of the reduce-MFMA A-fragment)
    if (t < 128) {
        const int tile = t >> 2, mm = (t >> 1) & 1, hh = t & 1;
        const float* src = plusT + (size_t)n * NM + tile * 32 + mm * 16 + hh * 4;
        f32x4 v0 = *(const f32x4*)(src);
        f32x4 v1 = *(const f32x4*)(src + 8);
        unsigned short* dst = plusbf + (size_t)((tile * 2 + mm) * 2 + hh) * 8;
        dst[0] = f2bf(v0.x); dst[1] = f2bf(v0.y); dst[2] = f2bf(v0.z); dst[3] = f2bf(v0.w);
        dst[4] = f2bf(v1.x); dst[5] = f2bf(v1.y); dst[6] = f2bf(v1.z); dst[7] = f2bf(v1.w);
    }

    // ================= phase 1: hat_phi tile (256 b x 64 h) =================
    const int eh = t >> 2, ei = (t & 3) * 16;
    const float* arow = Al + ((size_t)n * NH + eh) * NPOS + ei;
    const unsigned short* s0 = seq_bf + (size_t)(wv * 64 + r) * NPOS;        // bs=0
    const unsigned short* s1 = seq_bf + (size_t)(wv * 64 + 32 + r) * NPOS;   // bs=1

    f32x16 acc00, acc01, acc10, acc11;
#pragma unroll
    for (int i = 0; i < 16; i++) { acc00[i] = 0.f; acc01[i] = 0.f; acc10[i] = 0.f; acc11[i] = 0.f; }

    f32x4 ea[4];
    bf16x8 sc0[4], sc1[4], sn0[4], sn1[4];
#pragma unroll
    for (int g = 0; g < 4; g++) ea[g] = *(const f32x4*)(arow + g * 4);
#pragma unroll
    for (int kq = 0; kq < 4; kq++) {
        sc0[kq] = *(const bf16x8*)(s0 + kq * 16 + half * 8);
        sc1[kq] = *(const bf16x8*)(s1 + kq * 16 + half * 8);
    }
    __syncthreads();   // z_lds init + W table staged

    for (int kk = 0; kk < ksteps; kk++) {
        const int k0 = kk * 64;
        unsigned short* ebuf = (unsigned short*)e_lds[kk & 1];
        // 1. exp + stage E tile from regs (masked), accumulate Z
        {
            float zp = 0.f;
            unsigned short* ep = ebuf + eh * 72 + ei;
#pragma unroll
            for (int g = 0; g < 4; g++) {
                int i0 = k0 + ei + g * 4;
                float e0 = (i0 + 0 < n) ? __expf(ea[g].x) : 0.f;
                float e1 = (i0 + 1 < n) ? __expf(ea[g].y) : 0.f;
                float e2 = (i0 + 2 < n) ? __expf(ea[g].z) : 0.f;
                float e3 = (i0 + 3 < n) ? __expf(ea[g].w) : 0.f;
                zp += (e0 + e1) + (e2 + e3);
                int2 o; o.x = pack2(f2bf(e0), f2bf(e1)); o.y = pack2(f2bf(e2), f2bf(e3));
                *(int2*)(ep + g * 4) = o;
            }
            zp += __shfl_xor(zp, 1);
            zp += __shfl_xor(zp, 2);
            if ((t & 3) == 0) z_lds[eh] += zp;
        }
        // 2. prefetch k+1 (A row + S fragments) — stays in flight across barrier
        if (kk + 1 < ksteps) {
#pragma unroll
            for (int g = 0; g < 4; g++) ea[g] = *(const f32x4*)(arow + k0 + 64 + g * 4);
#pragma unroll
            for (int kq = 0; kq < 4; kq++) {
                sn0[kq] = *(const bf16x8*)(s0 + k0 + 64 + kq * 16 + half * 8);
                sn1[kq] = *(const bf16x8*)(s1 + k0 + 64 + kq * 16 + half * 8);
            }
        }
        // 3. LDS-only fence + raw barrier (global prefetches NOT drained)
        asm volatile("s_waitcnt lgkmcnt(0)" ::: "memory");
        __builtin_amdgcn_s_barrier();
        asm volatile("" ::: "memory");
        // 4. MFMA: D[b][h] += S[b,i] * E[h,i]
        {
            const unsigned short* sB0 = ebuf + r * 72;
            const unsigned short* sB1 = sB0 + 32 * 72;
#pragma unroll
            for (int kq = 0; kq < 4; kq++) {
                const int ko = kq * 16 + half * 8;
                bf16x8 B0 = *(const bf16x8*)(sB0 + ko);
                bf16x8 B1 = *(const bf16x8*)(sB1 + ko);
                acc00 = __builtin_amdgcn_mfma_f32_32x32x16_bf16(sc0[kq], B0, acc00, 0, 0, 0);
                acc01 = __builtin_amdgcn_mfma_f32_32x32x16_bf16(sc0[kq], B1, acc01, 0, 0, 0);
                acc10 = __builtin_amdgcn_mfma_f32_32x32x16_bf16(sc1[kq], B0, acc10, 0, 0, 0);
                acc11 = __builtin_amdgcn_mfma_f32_32x32x16_bf16(sc1[kq], B1, acc11, 0, 0, 0);
            }
        }
        // 5. rotate S fragments
        if (kk + 1 < ksteps) {
#pragma unroll
            for (int kq = 0; kq < 4; kq++) { sc0[kq] = sn0[kq]; sc1[kq] = sn1[kq]; }
        }
    }
    // epilogue: scale by 1/Z[h], write q tile into q_lds (wave-own rows; no
    // barrier needed before the same wave reads them back in phase 2).
    {
        float rz0 = 1.0f / z_lds[r];
        float rz1 = 1.0f / z_lds[32 + r];
#pragma unroll
        for (int reg = 0; reg < 16; reg++) {
            int row = (reg & 3) + 8 * (reg >> 2) + 4 * half;
            q_lds[(wv * 64 + row) * 72 + r]            = f2bf(acc00[reg] * rz0);
            q_lds[(wv * 64 + row) * 72 + 32 + r]       = f2bf(acc01[reg] * rz1);
            q_lds[(wv * 64 + 32 + row) * 72 + r]       = f2bf(acc10[reg] * rz0);
            q_lds[(wv * 64 + 32 + row) * 72 + 32 + r]  = f2bf(acc11[reg] * rz1);
        }
    }

    // ================= phase 2: retrieval softmax (MFMA-reduced) ============
    bf16x8 p[4], pn[4];
    p2_loadF(p, phimuF, 0, lane);              // coalesced; issue first
    bf16x8 q0[4], q1[4];
#pragma unroll
    for (int kq = 0; kq < 4; kq++) {
        q0[kq] = *(const bf16x8*)(q_lds + (wv * 64 + r) * 72 + kq * 16 + half * 8);
        q1[kq] = *(const bf16x8*)(q_lds + (wv * 64 + 32 + r) * 72 + kq * 16 + half * 8);
    }
    f32x16 zacc, accD0, accD1;
#pragma unroll
    for (int i = 0; i < 16; i++) { zacc[i] = 0.f; accD0[i] = 0.f; accD1[i] = 0.f; }

    // per-lane W-column constants: col 0 = ones, col 1 = plus, others 0
    const unsigned onespat = (r == 0) ? 0x3F803F80u : 0u;
    const unsigned pmask   = (r == 1) ? 0xFFFFFFFFu : 0u;

    for (int it = 0; it < 32; ++it) {
        if (it < 31) p2_loadF(pn, phimuF, it + 1, lane);   // prefetch, no barrier
        // score MFMAs: a0 (b 0..31), a1 (b 32..63)
        f32x16 a0, a1;
        a0 = __builtin_amdgcn_mfma_f32_32x32x16_bf16(p[0], q0[0], zacc, 0, 0, 0);
        a1 = __builtin_amdgcn_mfma_f32_32x32x16_bf16(p[0], q1[0], zacc, 0, 0, 0);
#pragma unroll
        for (int kq = 1; kq < 4; kq++) {
            a0 = __builtin_amdgcn_mfma_f32_32x32x16_bf16(p[kq], q0[kq], a0, 0, 0, 0);
            a1 = __builtin_amdgcn_mfma_f32_32x32x16_bf16(p[kq], q1[kq], a1, 0, 0, 0);
        }
        // W fragments for this tile (broadcast LDS reads; k-order = sigma)
        i32x4 w1r = *(const i32x4*)(plusbf + (size_t)(4 * it + half) * 8);
        i32x4 w2r = *(const i32x4*)(plusbf + (size_t)(4 * it + 2 + half) * 8);
        i32x4 W1, W2;
        W1.x = onespat | (w1r.x & pmask); W1.y = onespat | (w1r.y & pmask);
        W1.z = onespat | (w1r.z & pmask); W1.w = onespat | (w1r.w & pmask);
        W2.x = onespat | (w2r.x & pmask); W2.y = onespat | (w2r.y & pmask);
        W2.z = onespat | (w2r.z & pmask); W2.w = onespat | (w2r.w & pmask);
        // exp -> bf16 A-fragments, reduce-MFMA into accD (col0=den, col1=num)
        {
            float e00 = EXP2F(a0[0]),  e01 = EXP2F(a0[1]),  e02 = EXP2F(a0[2]),  e03 = EXP2F(a0[3]);
            float e04 = EXP2F(a0[4]),  e05 = EXP2F(a0[5]),  e06 = EXP2F(a0[6]),  e07 = EXP2F(a0[7]);
            float e08 = EXP2F(a0[8]),  e09 = EXP2F(a0[9]),  e10 = EXP2F(a0[10]), e11 = EXP2F(a0[11]);
            float e12 = EXP2F(a0[12]), e13 = EXP2F(a0[13]), e14 = EXP2F(a0[14]), e15 = EXP2F(a0[15]);
            i32x4 A1, A2;
            A1.x = cvtpk(e00, e01); A1.y = cvtpk(e02, e03); A1.z = cvtpk(e04, e05); A1.w = cvtpk(e06, e07);
            A2.x = cvtpk(e08, e09); A2.y = cvtpk(e10, e11); A2.z = cvtpk(e12, e13); A2.w = cvtpk(e14, e15);
            accD0 = __builtin_amdgcn_mfma_f32_32x32x16_bf16(*(bf16x8*)&A1, *(bf16x8*)&W1, accD0, 0, 0, 0);
            accD0 = __builtin_amdgcn_mfma_f32_32x32x16_bf16(*(bf16x8*)&A2, *(bf16x8*)&W2, accD0, 0, 0, 0);
        }
        {
            float e00 = EXP2F(a1[0]),  e01 = EXP2F(a1[1]),  e02 = EXP2F(a1[2]),  e03 = EXP2F(a1[3]);
            float e04 = EXP2F(a1[4]),  e05 = EXP2F(a1[5]),  e06 = EXP2F(a1[6]),  e07 = EXP2F(a1[7]);
            float e08 = EXP2F(a1[8]),  e09 = EXP2F(a1[9]),  e10 = EXP2F(a1[10]), e11 = EXP2F(a1[11]);
            float e12 = EXP2F(a1[12]), e13 = EXP2F(a1[13]), e14 = EXP2F(a1[14]), e15 = EXP2F(a1[15]);
            i32x4 A1, A2;
            A1.x = cvtpk(e00, e01); A1.y = cvtpk(e02, e03); A1.z = cvtpk(e04, e05); A1.w = cvtpk(e06, e07);
            A2.x = cvtpk(e08, e09); A2.y = cvtpk(e10, e11); A2.z = cvtpk(e12, e13); A2.w = cvtpk(e14, e15);
            accD1 = __builtin_amdgcn_mfma_f32_32x32x16_bf16(*(bf16x8*)&A1, *(bf16x8*)&W1, accD1, 0, 0, 0);
            accD1 = __builtin_amdgcn_mfma_f32_32x32x16_bf16(*(bf16x8*)&A2, *(bf16x8*)&W2, accD1, 0, 0, 0);
        }
        if (it < 31) {
#pragma unroll
            for (int kq = 0; kq < 4; kq++) p[kq] = pn[kq];
        }
    }

    // formal fence: all waves done reading e_lds (phase 1) before reuse below
    __syncthreads();
    // accD layout: col r==0 holds den[b=rowmap], col r==1 holds num.
    float* dsum = (float*)e_lds;          // 256 floats (e_lds dead after phase 1)
    float* nsum = dsum + 256;
    if (r < 2) {
        float* dst = (r == 0) ? dsum : nsum;
#pragma unroll
        for (int reg = 0; reg < 16; reg++) {
            int row = (reg & 3) + 8 * (reg >> 2) + 4 * half;
            dst[wv * 64 + row]      = accD0[reg];
            dst[wv * 64 + 32 + row] = accD1[reg];
        }
    }
    __syncthreads();
    // BCE for b = t
    {
        float dd = dsum[t], nn = nsum[t];
        float p2 = nn / dd;
        p2 = fminf(fmaxf(p2, 1e-6f), 1.0f - 1e-6f);
        float tg = seq[(size_t)t * NPOS + n];
        float bce = (tg > 0.f) ? -logf(p2) : -logf(1.0f - p2);
#pragma unroll
        for (int o = 32; o; o >>= 1) bce += __shfl_xor(bce, o);
        if (lane == 0) w_lds[wv] = bce;
    }
    __syncthreads();
    if (t == 0)
        atomicAdd(out, (w_lds[0] + w_lds[1] + w_lds[2] + w_lds[3]) * (1.0f / 130816.0f));
}

extern "C" void kernel_launch(void* const* d_in, const int* in_sizes, int n_in,
                              void* d_out, int out_size, void* d_ws, size_t ws_size,
                              hipStream_t stream) {
    const float* seq = (const float*)d_in[0];  // (B,N)
    const float* mem = (const float*)d_in[1];  // (M,N)
    const float* Al  = (const float*)d_in[2];  // (N,H,N)
    const float* Bl  = (const float*)d_in[3];  // (H,N)

    char* ws = (char*)d_ws;
    unsigned short* seq_bf = (unsigned short*)(ws + 0);          // 256 KB
    float*          BnT    = (float*)(ws + 262144);              // 128 KB (N,H)
    unsigned short* phimuF = (unsigned short*)(ws + 393216);     // 128 KB fragment layout
    float*          plusT  = (float*)(ws + 524288);              // 2 MB (N,M)
    float*          outp   = (float*)d_out;                      // total 2.6 MB (proven R0-R3)

    kA_prep<<<272, 256, 0, stream>>>(seq, Bl, mem, seq_bf, BnT, plusT, outp);
    k1b_phimu<<<128, 256, 0, stream>>>(BnT, mem, phimuF);
    k23_fused<<<511, 256, 0, stream>>>(Al, seq_bf, phimuF, plusT, seq, outp);
}